// Round 1
// baseline (513.076 us; speedup 1.0000x reference)
//
#include <hip/hip_runtime.h>
#include <cstdint>
#include <cstddef>

typedef unsigned short u16;
typedef unsigned int u32;
typedef float f32x4 __attribute__((ext_vector_type(4)));
typedef short short8 __attribute__((ext_vector_type(8)));

#define HW 196
#define DIM 1024
#define HD 64
#define SP 208
#define SPV 224
#define NBH 1024

__device__ __forceinline__ float bf2f(u16 x){
  union { u32 u; float f; } c; c.u = ((u32)x) << 16; return c.f;
}
__device__ __forceinline__ u16 f2bf(float f){
  union { float f; u32 u; } c; c.f = f;
  return (u16)((c.u + 0x7fffu + ((c.u >> 16) & 1u)) >> 16);
}

// ---- weight transpose + convert: w[K][N] f32 -> wT[N][K] bf16 ----
__global__ __launch_bounds__(256) void k_wT(const float* __restrict__ w,
                                            u16* __restrict__ wT, int K, int N){
  __shared__ float t[32][33];
  int n0 = blockIdx.x * 32, k0 = blockIdx.y * 32;
  int c = threadIdx.x & 31, rr = threadIdx.x >> 5;
  #pragma unroll
  for (int i = 0; i < 4; ++i){
    int r = rr + i*8;
    t[r][c] = w[(size_t)(k0 + r) * N + n0 + c];
  }
  __syncthreads();
  #pragma unroll
  for (int i = 0; i < 4; ++i){
    int r = rr + i*8;
    wT[(size_t)(n0 + r) * K + k0 + c] = f2bf(t[c][r]);
  }
}

// ---- GEMM: C[M][128*gy] = A[M][K] * Bt[N][K]^T + bias ----
// MODE 0: A = f32 (x); epilogue scatters bf16 into q/k [bh][208][64] and vT [bh][64][224]
// MODE 1: A = bf16 (attn out); epilogue writes f32 out + bias
template<int MODE>
__global__ __launch_bounds__(256) void k_gemm(const void* __restrict__ Ain,
    const u16* __restrict__ Bt, const float* __restrict__ bias,
    u16* __restrict__ qg, u16* __restrict__ kg, u16* __restrict__ vTg,
    float* __restrict__ outf, int K, int N)
{
  __shared__ __align__(16) u16 As[128*64];
  __shared__ __align__(16) u16 Bs[128*64];
  const int tid = threadIdx.x;
  const int lane = tid & 63, wv = tid >> 6, wr = wv >> 1, wc = wv & 1;
  const int l16 = lane & 15, lk = lane >> 4;
  const size_t m0 = (size_t)blockIdx.x * 128;
  const size_t n0 = (size_t)blockIdx.y * 128;
  const int nk = K >> 6;
  const float* Af = (const float*)Ain;
  const u16*  Ab = (const u16*)Ain;
  const int trow = tid >> 3;          // staging row-within-32
  const int tcb  = (tid & 7) << 4;    // byte col 0..112
  const int swz  = (trow & 7) << 4;

  f32x4 fa[4][2]; short8 ra[4]; short8 rb[4];
  f32x4 acc[4][4] = {};

  auto load_tiles = [&](int kt){
    #pragma unroll
    for (int j = 0; j < 4; ++j){
      int grow = j*32 + trow;
      int ecol = kt*64 + (tcb >> 1);
      if constexpr (MODE == 0){
        const f32x4* p = (const f32x4*)(Af + (m0 + grow) * (size_t)K + ecol);
        fa[j][0] = p[0]; fa[j][1] = p[1];
      } else {
        ra[j] = *(const short8*)(Ab + (m0 + grow) * (size_t)K + ecol);
      }
      rb[j] = *(const short8*)(Bt + (n0 + grow) * (size_t)K + ecol);
    }
  };
  auto store_tiles = [&](){
    #pragma unroll
    for (int j = 0; j < 4; ++j){
      int loff = j*4096 + trow*128 + (tcb ^ swz);
      if constexpr (MODE == 0){
        short8 t;
        #pragma unroll
        for (int e = 0; e < 4; ++e){
          t[e]   = (short)f2bf(fa[j][0][e]);
          t[4+e] = (short)f2bf(fa[j][1][e]);
        }
        *(short8*)((char*)As + loff) = t;
      } else {
        *(short8*)((char*)As + loff) = ra[j];
      }
      *(short8*)((char*)Bs + loff) = rb[j];
    }
  };

  load_tiles(0);
  #pragma unroll 1
  for (int kt = 0; kt < nk; ++kt){
    __syncthreads();
    store_tiles();
    __syncthreads();
    if (kt + 1 < nk) load_tiles(kt + 1);
    #pragma unroll
    for (int ks = 0; ks < 2; ++ks){
      short8 a[4], b[4];
      #pragma unroll
      for (int mi = 0; mi < 4; ++mi){
        int row = wr*64 + mi*16 + l16;
        int c2 = ks*64 + lk*16;
        a[mi] = *(const short8*)((const char*)As + (row << 7) + (c2 ^ ((row & 7) << 4)));
      }
      #pragma unroll
      for (int ni = 0; ni < 4; ++ni){
        int row = wc*64 + ni*16 + l16;
        int c2 = ks*64 + lk*16;
        b[ni] = *(const short8*)((const char*)Bs + (row << 7) + (c2 ^ ((row & 7) << 4)));
      }
      #pragma unroll
      for (int mi = 0; mi < 4; ++mi)
        #pragma unroll
        for (int ni = 0; ni < 4; ++ni)
          acc[mi][ni] = __builtin_amdgcn_mfma_f32_16x16x32_bf16(a[mi], b[ni], acc[mi][ni], 0, 0, 0);
    }
  }

  const int rowb = (int)m0 + wr*64;
  const int colb = (int)n0 + wc*64;
  #pragma unroll
  for (int ni = 0; ni < 4; ++ni){
    int ccol = colb + ni*16 + l16;
    float bs = bias[ccol];
    #pragma unroll
    for (int mi = 0; mi < 4; ++mi){
      #pragma unroll
      for (int i = 0; i < 4; ++i){
        int r = rowb + mi*16 + lk*4 + i;
        float v = acc[mi][ni][i] + bs;
        if constexpr (MODE == 0){
          int t3 = ccol >> 10, rem = ccol & 1023, h = rem >> 6, cc = rem & 63;
          int b = r / 196;
          int n = r - b * 196;
          int bhh = h * 64 + b;
          u16 bv = f2bf(v);
          if (t3 == 0)      qg[((size_t)bhh * SP + n) * HD + cc] = bv;
          else if (t3 == 1) kg[((size_t)bhh * SP + n) * HD + cc] = bv;
          else              vTg[((size_t)bhh * HD + cc) * SPV + n] = bv;
        } else {
          outf[(size_t)r * N + ccol] = v;
        }
      }
    }
  }
}

// ---- fused attention: one block per (head,batch) ----
__global__ __launch_bounds__(256) void k_attn(
    const u16* __restrict__ qg, const u16* __restrict__ kg, const u16* __restrict__ vTg,
    const float* __restrict__ rph, const float* __restrict__ rpw,
    u16* __restrict__ ao)
{
  __shared__ __align__(16) u16 Ks[HW * 64];      // 196x64 bf16, XOR-swizzled (25088 B)
  __shared__ __align__(16) u16 relb[HW * 28];    // rel_h|rel_w per q-row (10976 B)
  __shared__ __align__(16) u16 Pst[4][16 * SPV]; // per-wave P staging (28672 B)
  const int tid = threadIdx.x, lane = tid & 63, wvi = tid >> 6;
  const int l16 = lane & 15, lk = lane >> 4;
  const int bh = blockIdx.x;
  const int hh = bh >> 6, bb = bh & 63;
  const u16* qb = qg + (size_t)bh * SP * HD;
  const u16* kb = kg + (size_t)bh * SP * HD;
  const u16* vb = vTg + (size_t)bh * HD * SPV;

  // stage K rows (196) into swizzled LDS
  for (int c = tid; c < (HW * 128 / 16); c += 256){
    int off = c << 4, row = off >> 7, cb = off & 127;
    short8 d = *(const short8*)((const char*)kb + off);
    *(short8*)((char*)Ks + (row << 7) + (cb ^ ((row & 7) << 4))) = d;
  }
  // decomposed rel-pos terms: relb[r][j] = q_r . Rh[qh][j],  relb[r][14+j] = q_r . Rw[qw][j]
  if (tid < HW){
    int r = tid, qh = r / 14, qw = r - qh * 14;
    short8 qv[8];
    #pragma unroll
    for (int j = 0; j < 8; ++j) qv[j] = *(const short8*)(qb + (size_t)r * HD + j * 8);
    #pragma unroll 1
    for (int j = 0; j < 14; ++j){
      const float* Rh = rph + (size_t)(qh - j + 13) * HD;
      const float* Rw = rpw + (size_t)(qw - j + 13) * HD;
      float ah = 0.f, aw = 0.f;
      #pragma unroll
      for (int vv = 0; vv < 8; ++vv){
        #pragma unroll
        for (int e = 0; e < 8; ++e){
          float qf = bf2f((u16)qv[vv][e]);
          ah += qf * Rh[vv*8 + e];
          aw += qf * Rw[vv*8 + e];
        }
      }
      relb[r*28 + j] = f2bf(ah);
      relb[r*28 + 14 + j] = f2bf(aw);
    }
  }
  __syncthreads();

  #pragma unroll 1
  for (int g = 0; g < 4; ++g){
    int mt = g*4 + wvi;
    bool act = (mt < 13);
    if (act){
      f32x4 z = {0.f, 0.f, 0.f, 0.f};
      f32x4 sacc[13];
      #pragma unroll
      for (int nt = 0; nt < 13; ++nt) sacc[nt] = z;
      const short8 a0 = *(const short8*)(qb + (size_t)(mt*16 + l16) * HD + lk*8);
      const short8 a1 = *(const short8*)(qb + (size_t)(mt*16 + l16) * HD + 32 + lk*8);
      #pragma unroll
      for (int nt = 0; nt < 13; ++nt){
        int row = nt*16 + l16; if (row > HW-1) row = HW-1;   // clamp pad keys (masked later)
        int c2a = lk*16, c2b = 64 + lk*16;
        short8 b0 = *(const short8*)((const char*)Ks + (row << 7) + (c2a ^ ((row & 7) << 4)));
        short8 b1 = *(const short8*)((const char*)Ks + (row << 7) + (c2b ^ ((row & 7) << 4)));
        sacc[nt] = __builtin_amdgcn_mfma_f32_16x16x32_bf16(a0, b0, sacc[nt], 0, 0, 0);
        sacc[nt] = __builtin_amdgcn_mfma_f32_16x16x32_bf16(a1, b1, sacc[nt], 0, 0, 0);
      }
      #pragma unroll
      for (int nt = 0; nt < 13; ++nt){
        int key = nt*16 + l16;
        int kh = key / 14, kw = key - kh*14;
        bool kok = key < HW;
        #pragma unroll
        for (int i = 0; i < 4; ++i){
          int qrow = mt*16 + lk*4 + i;
          float s;
          if (!kok) s = -1e30f;
          else {
            s = sacc[nt][i] * 0.125f;
            if (qrow < HW) s += bf2f(relb[qrow*28 + kh]) + bf2f(relb[qrow*28 + 14 + kw]);
          }
          sacc[nt][i] = s;
        }
      }
      // softmax across the row (13 tiles x 16 lanes of same lk-group)
      #pragma unroll
      for (int i = 0; i < 4; ++i){
        float m = -1e30f;
        #pragma unroll
        for (int nt = 0; nt < 13; ++nt) m = fmaxf(m, sacc[nt][i]);
        #pragma unroll
        for (int d = 1; d < 16; d <<= 1) m = fmaxf(m, __shfl_xor(m, d, 64));
        float sum = 0.f;
        #pragma unroll
        for (int nt = 0; nt < 13; ++nt){
          float p = __expf(sacc[nt][i] - m);
          sacc[nt][i] = p; sum += p;
        }
        #pragma unroll
        for (int d = 1; d < 16; d <<= 1) sum += __shfl_xor(sum, d, 64);
        float inv = 1.f / sum;
        #pragma unroll
        for (int nt = 0; nt < 13; ++nt) sacc[nt][i] *= inv;
      }
      // write P bf16 to per-wave LDS staging (swizzled for cols < 192)
      char* pbase = (char*)Pst[wvi];
      #pragma unroll
      for (int nt = 0; nt < 14; ++nt){
        #pragma unroll
        for (int i = 0; i < 4; ++i){
          int prow = lk*4 + i;
          int key = nt*16 + l16;
          float pv = (nt < 13) ? sacc[nt][i] : 0.f;
          if (key >= HW) pv = 0.f;          // masked keys exactly zero (NaN-safe)
          int c2 = key * 2;
          if (nt < 12) c2 ^= (prow & 7) << 4;
          *(u16*)(pbase + prow*448 + c2) = f2bf(pv);
        }
      }
    }
    __syncthreads();
    if (act){
      const char* pbase = (const char*)Pst[wvi];
      f32x4 z = {0.f,0.f,0.f,0.f};
      f32x4 oacc[4];
      #pragma unroll
      for (int n = 0; n < 4; ++n) oacc[n] = z;
      #pragma unroll
      for (int kt = 0; kt < 7; ++kt){
        int c2 = kt*64 + lk*16;
        if (kt < 6) c2 ^= (l16 & 7) << 4;
        short8 pa = *(const short8*)(pbase + l16*448 + c2);
        #pragma unroll
        for (int n = 0; n < 4; ++n){
          short8 bv = *(const short8*)(vb + (size_t)(n*16 + l16) * SPV + kt*32 + lk*8);
          oacc[n] = __builtin_amdgcn_mfma_f32_16x16x32_bf16(pa, bv, oacc[n], 0, 0, 0);
        }
      }
      #pragma unroll
      for (int n = 0; n < 4; ++n){
        int cc = n*16 + l16;
        #pragma unroll
        for (int i = 0; i < 4; ++i){
          int qrow = mt*16 + lk*4 + i;
          if (qrow < HW)
            ao[((size_t)bb * HW + qrow) * DIM + hh * HD + cc] = f2bf(oacc[n][i]);
        }
      }
    }
    __syncthreads();
  }
}

extern "C" void kernel_launch(void* const* d_in, const int* in_sizes, int n_in,
                              void* d_out, int out_size, void* d_ws, size_t ws_size,
                              hipStream_t stream)
{
  const float* x      = (const float*)d_in[0];
  const float* qkv_w  = (const float*)d_in[1];
  const float* qkv_b  = (const float*)d_in[2];
  const float* proj_w = (const float*)d_in[3];
  const float* proj_b = (const float*)d_in[4];
  const float* rph    = (const float*)d_in[5];
  const float* rpw    = (const float*)d_in[6];
  float* out = (float*)d_out;
  char* ws = (char*)d_ws;

  size_t off = 0;
  auto alloc = [&](size_t b){ size_t r = off; off += (b + 255) & ~(size_t)255; return r; };
  u16* wqkvT = (u16*)(ws + alloc((size_t)3072*1024*2));
  u16* wprojT= (u16*)(ws + alloc((size_t)1024*1024*2));
  u16* qg    = (u16*)(ws + alloc((size_t)NBH*SP*HD*2));
  u16* kg    = (u16*)(ws + alloc((size_t)NBH*SP*HD*2));
  u16* vTg   = (u16*)(ws + alloc((size_t)NBH*HD*SPV*2));
  u16* ao    = (u16*)(ws + alloc((size_t)12544*1024*2));

  // zero V^T so padded key-columns are exactly 0 (they enter the PV contraction)
  hipMemsetAsync(vTg, 0, (size_t)NBH*HD*SPV*2, stream);

  k_wT<<<dim3(96, 32), 256, 0, stream>>>(qkv_w, wqkvT, 1024, 3072);
  k_wT<<<dim3(32, 32), 256, 0, stream>>>(proj_w, wprojT, 1024, 1024);
  k_gemm<0><<<dim3(98, 24), 256, 0, stream>>>(x, wqkvT, qkv_b, qg, kg, vTg, nullptr, 1024, 3072);
  k_attn<<<1024, 256, 0, stream>>>(qg, kg, vTg, rph, rpw, ao);
  k_gemm<1><<<dim3(98, 8), 256, 0, stream>>>(ao, wprojT, proj_b, nullptr, nullptr, nullptr, out, 1024, 1024);
}

// Round 2
// 459.823 us; speedup vs baseline: 1.1158x; 1.1158x over previous
//
#include <hip/hip_runtime.h>
#include <cstdint>
#include <cstddef>

typedef unsigned short u16;
typedef unsigned int u32;
typedef float f32x4 __attribute__((ext_vector_type(4)));
typedef float f32x2 __attribute__((ext_vector_type(2)));
typedef short short8 __attribute__((ext_vector_type(8)));

#define HW 196
#define DIM 1024
#define HD 64
#define SP 208
#define SPV 224
#define NBH 1024

__device__ __forceinline__ float bf2f(u16 x){
  union { u32 u; float f; } c; c.u = ((u32)x) << 16; return c.f;
}
__device__ __forceinline__ u16 f2bf(float f){
  union { float f; u32 u; } c; c.f = f;
  return (u16)((c.u + 0x7fffu + ((c.u >> 16) & 1u)) >> 16);
}

// ---- weight transpose + convert: w[K][N] f32 -> wT[N][K] bf16 ----
__global__ __launch_bounds__(256) void k_wT(const float* __restrict__ w,
                                            u16* __restrict__ wT, int K, int N){
  __shared__ float t[32][33];
  int n0 = blockIdx.x * 32, k0 = blockIdx.y * 32;
  int c = threadIdx.x & 31, rr = threadIdx.x >> 5;
  #pragma unroll
  for (int i = 0; i < 4; ++i){
    int r = rr + i*8;
    t[r][c] = w[(size_t)(k0 + r) * N + n0 + c];
  }
  __syncthreads();
  #pragma unroll
  for (int i = 0; i < 4; ++i){
    int r = rr + i*8;
    wT[(size_t)(n0 + r) * K + k0 + c] = f2bf(t[c][r]);
  }
}

// ---- GEMM: C[M][128*gy] = A[M][K] * Bt[N][K]^T + bias ----
// MODE 0: A = f32 (x); epilogue scatters bf16 into q/k [bh][208][64] and vT [bh][64][224]
// MODE 1: A = bf16 (attn out); epilogue writes f32 out + bias
template<int MODE>
__global__ __launch_bounds__(256) void k_gemm(const void* __restrict__ Ain,
    const u16* __restrict__ Bt, const float* __restrict__ bias,
    u16* __restrict__ qg, u16* __restrict__ kg, u16* __restrict__ vTg,
    float* __restrict__ outf, int K, int N)
{
  __shared__ __align__(16) u16 As[128*64];
  __shared__ __align__(16) u16 Bs[128*64];
  const int tid = threadIdx.x;
  const int lane = tid & 63, wv = tid >> 6, wr = wv >> 1, wc = wv & 1;
  const int l16 = lane & 15, lk = lane >> 4;
  const size_t m0 = (size_t)blockIdx.x * 128;
  const size_t n0 = (size_t)blockIdx.y * 128;
  const int nk = K >> 6;
  const float* Af = (const float*)Ain;
  const u16*  Ab = (const u16*)Ain;
  const int trow = tid >> 3;          // staging row-within-32
  const int tcb  = (tid & 7) << 4;    // byte col 0..112
  const int swz  = (trow & 7) << 4;

  f32x4 fa[4][2]; short8 ra[4]; short8 rb[4];
  f32x4 acc[4][4] = {};

  auto load_tiles = [&](int kt){
    #pragma unroll
    for (int j = 0; j < 4; ++j){
      int grow = j*32 + trow;
      int ecol = kt*64 + (tcb >> 1);
      if constexpr (MODE == 0){
        const f32x4* p = (const f32x4*)(Af + (m0 + grow) * (size_t)K + ecol);
        fa[j][0] = p[0]; fa[j][1] = p[1];
      } else {
        ra[j] = *(const short8*)(Ab + (m0 + grow) * (size_t)K + ecol);
      }
      rb[j] = *(const short8*)(Bt + (n0 + grow) * (size_t)K + ecol);
    }
  };
  auto store_tiles = [&](){
    #pragma unroll
    for (int j = 0; j < 4; ++j){
      int loff = j*4096 + trow*128 + (tcb ^ swz);
      if constexpr (MODE == 0){
        short8 t;
        #pragma unroll
        for (int e = 0; e < 4; ++e){
          t[e]   = (short)f2bf(fa[j][0][e]);
          t[4+e] = (short)f2bf(fa[j][1][e]);
        }
        *(short8*)((char*)As + loff) = t;
      } else {
        *(short8*)((char*)As + loff) = ra[j];
      }
      *(short8*)((char*)Bs + loff) = rb[j];
    }
  };

  load_tiles(0);
  #pragma unroll 1
  for (int kt = 0; kt < nk; ++kt){
    __syncthreads();
    store_tiles();
    __syncthreads();
    if (kt + 1 < nk) load_tiles(kt + 1);
    #pragma unroll
    for (int ks = 0; ks < 2; ++ks){
      short8 a[4], b[4];
      #pragma unroll
      for (int mi = 0; mi < 4; ++mi){
        int row = wr*64 + mi*16 + l16;
        int c2 = ks*64 + lk*16;
        a[mi] = *(const short8*)((const char*)As + (row << 7) + (c2 ^ ((row & 7) << 4)));
      }
      #pragma unroll
      for (int ni = 0; ni < 4; ++ni){
        int row = wc*64 + ni*16 + l16;
        int c2 = ks*64 + lk*16;
        b[ni] = *(const short8*)((const char*)Bs + (row << 7) + (c2 ^ ((row & 7) << 4)));
      }
      #pragma unroll
      for (int mi = 0; mi < 4; ++mi)
        #pragma unroll
        for (int ni = 0; ni < 4; ++ni)
          acc[mi][ni] = __builtin_amdgcn_mfma_f32_16x16x32_bf16(a[mi], b[ni], acc[mi][ni], 0, 0, 0);
    }
  }

  const int rowb = (int)m0 + wr*64;
  const int colb = (int)n0 + wc*64;
  #pragma unroll
  for (int ni = 0; ni < 4; ++ni){
    int ccol = colb + ni*16 + l16;
    float bs = bias[ccol];
    #pragma unroll
    for (int mi = 0; mi < 4; ++mi){
      #pragma unroll
      for (int i = 0; i < 4; ++i){
        int r = rowb + mi*16 + lk*4 + i;
        float v = acc[mi][ni][i] + bs;
        if constexpr (MODE == 0){
          int t3 = ccol >> 10, rem = ccol & 1023, h = rem >> 6, cc = rem & 63;
          int b = r / 196;
          int n = r - b * 196;
          int bhh = h * 64 + b;
          u16 bv = f2bf(v);
          if (t3 == 0)      qg[((size_t)bhh * SP + n) * HD + cc] = bv;
          else if (t3 == 1) kg[((size_t)bhh * SP + n) * HD + cc] = bv;
          else              vTg[((size_t)bhh * HD + cc) * SPV + n] = bv;
        } else {
          outf[(size_t)r * N + ccol] = v;
        }
      }
    }
  }
}

// ---- fused attention: one WAVE per (bh, q-tile) job; 4 waves/block, no lockstep ----
// jobs = 1024 bh * 13 qtiles = 13312 = 3328 blocks * 4 waves.
// LDS per wave: P staging 16x224 bf16 (7168 B) + rel table 16x28 f32 (1792 B).
__global__ __launch_bounds__(256) void k_attn(
    const u16* __restrict__ qg, const u16* __restrict__ kg, const u16* __restrict__ vTg,
    const float* __restrict__ rph, const float* __restrict__ rpw,
    u16* __restrict__ ao)
{
  __shared__ __align__(16) char smem[4 * 8960];
  const int tid = threadIdx.x, lane = tid & 63, wvi = tid >> 6;
  const int l16 = lane & 15, lk = lane >> 4;
  char*  pbase = smem + wvi * 8960;            // 16 x 224 bf16, swizzled cols<384B
  float* relf  = (float*)(pbase + 7168);       // [16][28] f32

  // XCD-chunked job assignment: 416 consecutive blocks per XCD -> bh-local L2 reuse
  int b = blockIdx.x;
  int sb = (b & 7) * 416 + (b >> 3);
  int j  = sb * 4 + wvi;
  int bh = j / 13;
  int mt = j - bh * 13;
  const int hh = bh >> 6, bb = bh & 63;
  const u16* qb = qg  + (size_t)bh * SP * HD;
  const u16* kb = kg  + (size_t)bh * SP * HD;
  const u16* vb = vTg + (size_t)bh * HD * SPV;

  // ---- rel-pos phase: lane (l16=row, lk) computes 7 of 28 dot products for its row ----
  {
    int qrow = mt*16 + l16;
    int qrc = qrow > HW-1 ? HW-1 : qrow;       // clamp index math only (pad rows discarded later)
    int qh = qrc / 14, qw = qrc - qh * 14;
    short8 qv[8];
    #pragma unroll
    for (int v = 0; v < 8; ++v) qv[v] = *(const short8*)(qb + (size_t)qrow * HD + v * 8);
    f32x2 qf[32];
    #pragma unroll
    for (int v = 0; v < 8; ++v)
      #pragma unroll
      for (int e = 0; e < 4; ++e){
        f32x2 t; t[0] = bf2f((u16)qv[v][2*e]); t[1] = bf2f((u16)qv[v][2*e+1]);
        qf[v*4 + e] = t;
      }
    #pragma unroll
    for (int c = 0; c < 7; ++c){
      int col = lk * 7 + c;
      const float* R = (col < 14) ? (rph + (size_t)(qh - col + 13) * HD)
                                  : (rpw + (size_t)(qw - (col - 14) + 13) * HD);
      f32x2 a2 = {0.f, 0.f};
      #pragma unroll
      for (int p = 0; p < 32; ++p){
        f32x2 rr = *(const f32x2*)(R + p * 2);
        a2 += qf[p] * rr;
      }
      relf[l16 * 28 + col] = a2[0] + a2[1];
    }
  }
  __syncthreads();

  // ---- QK^T: B-fragments straight from global (L2-resident K) ----
  f32x4 z = {0.f, 0.f, 0.f, 0.f};
  f32x4 sacc[13];
  #pragma unroll
  for (int nt = 0; nt < 13; ++nt) sacc[nt] = z;
  const short8 a0 = *(const short8*)(qb + (size_t)(mt*16 + l16) * HD + lk*8);
  const short8 a1 = *(const short8*)(qb + (size_t)(mt*16 + l16) * HD + 32 + lk*8);
  #pragma unroll
  for (int nt = 0; nt < 13; ++nt){
    int row = nt*16 + l16; if (row > HW-1) row = HW-1;   // clamp pad keys (masked below)
    short8 b0 = *(const short8*)(kb + (size_t)row * HD + lk*8);
    short8 b1 = *(const short8*)(kb + (size_t)row * HD + 32 + lk*8);
    sacc[nt] = __builtin_amdgcn_mfma_f32_16x16x32_bf16(a0, b0, sacc[nt], 0, 0, 0);
    sacc[nt] = __builtin_amdgcn_mfma_f32_16x16x32_bf16(a1, b1, sacc[nt], 0, 0, 0);
  }

  // ---- scale + rel bias + key mask ----
  #pragma unroll
  for (int nt = 0; nt < 13; ++nt){
    int key = nt*16 + l16;
    int kh = key / 14, kw = key - kh*14;
    bool kok = key < HW;
    #pragma unroll
    for (int i = 0; i < 4; ++i){
      int rloc = lk*4 + i;
      float s;
      if (!kok) s = -1e30f;
      else      s = sacc[nt][i] * 0.125f + relf[rloc*28 + kh] + relf[rloc*28 + 14 + kw];
      sacc[nt][i] = s;
    }
  }

  // ---- softmax over 196 keys (13 tiles x 16 l16-lanes, same lk = same q-row) ----
  #pragma unroll
  for (int i = 0; i < 4; ++i){
    float m = -1e30f;
    #pragma unroll
    for (int nt = 0; nt < 13; ++nt) m = fmaxf(m, sacc[nt][i]);
    #pragma unroll
    for (int d = 1; d < 16; d <<= 1) m = fmaxf(m, __shfl_xor(m, d, 64));
    float sum = 0.f;
    #pragma unroll
    for (int nt = 0; nt < 13; ++nt){
      float p = __expf(sacc[nt][i] - m);
      sacc[nt][i] = p; sum += p;
    }
    #pragma unroll
    for (int d = 1; d < 16; d <<= 1) sum += __shfl_xor(sum, d, 64);
    float inv = 1.f / sum;
    #pragma unroll
    for (int nt = 0; nt < 13; ++nt) sacc[nt][i] *= inv;
  }

  // ---- stage P (bf16) into per-wave LDS, swizzled for cols < 384 B ----
  #pragma unroll
  for (int nt = 0; nt < 14; ++nt){
    #pragma unroll
    for (int i = 0; i < 4; ++i){
      int prow = lk*4 + i;
      int key = nt*16 + l16;
      float pv = (nt < 13) ? sacc[nt][i] : 0.f;
      if (key >= HW || mt*16 + prow >= HW) pv = 0.f;  // NaN-safe: pad keys & pad q-rows
      int c2 = key * 2;
      if (nt < 12) c2 ^= (prow & 7) << 4;
      *(u16*)(pbase + prow*448 + c2) = f2bf(pv);
    }
  }
  // in-wave LDS write->read ordering (no barrier needed: buffer is wave-private)
  asm volatile("s_waitcnt lgkmcnt(0)" ::: "memory");
  __builtin_amdgcn_sched_barrier(0);

  // ---- PV: P from LDS (A-frag), V^T from global (B-frag) ----
  f32x4 oacc[4];
  #pragma unroll
  for (int n = 0; n < 4; ++n) oacc[n] = z;
  #pragma unroll
  for (int kt = 0; kt < 7; ++kt){
    int c2 = kt*64 + lk*16;
    if (kt < 6) c2 ^= (l16 & 7) << 4;
    short8 pa = *(const short8*)(pbase + l16*448 + c2);
    #pragma unroll
    for (int n = 0; n < 4; ++n){
      short8 bv = *(const short8*)(vb + (size_t)(n*16 + l16) * SPV + kt*32 + lk*8);
      oacc[n] = __builtin_amdgcn_mfma_f32_16x16x32_bf16(pa, bv, oacc[n], 0, 0, 0);
    }
  }
  #pragma unroll
  for (int n = 0; n < 4; ++n){
    int cc = n*16 + l16;
    #pragma unroll
    for (int i = 0; i < 4; ++i){
      int qrow = mt*16 + lk*4 + i;
      if (qrow < HW)
        ao[((size_t)bb * HW + qrow) * DIM + hh * HD + cc] = f2bf(oacc[n][i]);
    }
  }
}

extern "C" void kernel_launch(void* const* d_in, const int* in_sizes, int n_in,
                              void* d_out, int out_size, void* d_ws, size_t ws_size,
                              hipStream_t stream)
{
  const float* x      = (const float*)d_in[0];
  const float* qkv_w  = (const float*)d_in[1];
  const float* qkv_b  = (const float*)d_in[2];
  const float* proj_w = (const float*)d_in[3];
  const float* proj_b = (const float*)d_in[4];
  const float* rph    = (const float*)d_in[5];
  const float* rpw    = (const float*)d_in[6];
  float* out = (float*)d_out;
  char* ws = (char*)d_ws;

  size_t off = 0;
  auto alloc = [&](size_t b){ size_t r = off; off += (b + 255) & ~(size_t)255; return r; };
  u16* wqkvT = (u16*)(ws + alloc((size_t)3072*1024*2));
  u16* wprojT= (u16*)(ws + alloc((size_t)1024*1024*2));
  u16* qg    = (u16*)(ws + alloc((size_t)NBH*SP*HD*2));
  u16* kg    = (u16*)(ws + alloc((size_t)NBH*SP*HD*2));
  u16* vTg   = (u16*)(ws + alloc((size_t)NBH*HD*SPV*2));
  u16* ao    = (u16*)(ws + alloc((size_t)12544*1024*2));

  // zero V^T so padded key-columns are exactly 0 (they enter the PV contraction)
  hipMemsetAsync(vTg, 0, (size_t)NBH*HD*SPV*2, stream);

  k_wT<<<dim3(96, 32), 256, 0, stream>>>(qkv_w, wqkvT, 1024, 3072);
  k_wT<<<dim3(32, 32), 256, 0, stream>>>(proj_w, wprojT, 1024, 1024);
  k_gemm<0><<<dim3(98, 24), 256, 0, stream>>>(x, wqkvT, qkv_b, qg, kg, vTg, nullptr, 1024, 3072);
  k_attn<<<3328, 256, 0, stream>>>(qg, kg, vTg, rph, rpw, ao);
  k_gemm<1><<<dim3(98, 8), 256, 0, stream>>>(ao, wprojT, proj_b, nullptr, nullptr, nullptr, out, 1024, 1024);
}

// Round 3
// 413.951 us; speedup vs baseline: 1.2395x; 1.1108x over previous
//
#include <hip/hip_runtime.h>
#include <cstdint>
#include <cstddef>

typedef unsigned short u16;
typedef unsigned int u32;
typedef float f32x4 __attribute__((ext_vector_type(4)));
typedef float f32x2 __attribute__((ext_vector_type(2)));
typedef short short8 __attribute__((ext_vector_type(8)));

#define HW 196
#define DIM 1024
#define HD 64
#define SP 208
#define SPV 224
#define NBH 1024

__device__ __forceinline__ float bf2f(u16 x){
  union { u32 u; float f; } c; c.u = ((u32)x) << 16; return c.f;
}
__device__ __forceinline__ u16 f2bf(float f){
  union { float f; u32 u; } c; c.f = f;
  return (u16)((c.u + 0x7fffu + ((c.u >> 16) & 1u)) >> 16);
}

typedef __attribute__((address_space(3))) void lds_void_t;
typedef __attribute__((address_space(1))) const void glb_void_t;
__device__ __forceinline__ void gload_lds16(const void* g, void* l){
  __builtin_amdgcn_global_load_lds((glb_void_t*)g, (lds_void_t*)l, 16, 0, 0);
}

// ---- x f32 -> bf16 convert ----
__global__ __launch_bounds__(256) void k_xcvt(const float* __restrict__ x,
                                              u16* __restrict__ xb, int n8){
  int i = blockIdx.x * 256 + threadIdx.x;
  if (i < n8){
    const f32x4* p = (const f32x4*)(x + (size_t)i * 8);
    f32x4 v0 = p[0], v1 = p[1];
    short8 t;
    #pragma unroll
    for (int e = 0; e < 4; ++e){
      t[e]   = (short)f2bf(v0[e]);
      t[4+e] = (short)f2bf(v1[e]);
    }
    *(short8*)(xb + (size_t)i * 8) = t;
  }
}

// ---- weight transpose + convert: w[K][N] f32 -> wT[N][K] bf16 ----
__global__ __launch_bounds__(256) void k_wT(const float* __restrict__ w,
                                            u16* __restrict__ wT, int K, int N){
  __shared__ float t[32][33];
  int n0 = blockIdx.x * 32, k0 = blockIdx.y * 32;
  int c = threadIdx.x & 31, rr = threadIdx.x >> 5;
  #pragma unroll
  for (int i = 0; i < 4; ++i){
    int r = rr + i*8;
    t[r][c] = w[(size_t)(k0 + r) * N + n0 + c];
  }
  __syncthreads();
  #pragma unroll
  for (int i = 0; i < 4; ++i){
    int r = rr + i*8;
    wT[(size_t)(n0 + r) * K + k0 + c] = f2bf(t[c][r]);
  }
}

// ---- GEMM (m97 structure): C[128ry][128cy] = A[M][K](bf16) * Bt[N][K]^T + bias ----
// global_load_lds width-16 staging, linear LDS, 2-barrier K-loop, GROUP_M=8 + XCD chunking.
// MODE 0: epilogue scatters bf16 into q/k [bh][208][64] and vT [bh][64][224]
// MODE 1: epilogue writes f32 out + bias
template<int MODE>
__global__ __launch_bounds__(256) void k_gemm(const u16* __restrict__ Ab,
    const u16* __restrict__ Bt, const float* __restrict__ bias,
    u16* __restrict__ qg, u16* __restrict__ kg, u16* __restrict__ vTg,
    float* __restrict__ outf, int K, int N, int ntm, int ntn)
{
  __shared__ __align__(16) u16 As[128*64];
  __shared__ __align__(16) u16 Bs[128*64];
  const int tid = threadIdx.x;
  const int lane = tid & 63, wv = tid >> 6, wr = wv >> 1, wc = wv & 1;
  const int l16 = lane & 15, lk = lane >> 4;

  // bijective XCD chunking (m204) over GROUP_M=8 serpentine linearization
  const int nwg = ntm * ntn;
  int bid = blockIdx.x;
  int q8 = nwg >> 3, r8 = nwg & 7;
  int xcd = bid & 7, loc = bid >> 3;
  int wgid = (xcd < r8 ? xcd*(q8+1) : r8*(q8+1) + (xcd - r8)*q8) + loc;
  int gsz = 8 * ntn;
  int g = wgid / gsz, rem = wgid - g * gsz;
  int gm = ntm - g * 8; if (gm > 8) gm = 8;
  int ry = g * 8 + rem % gm;
  int cy = rem / gm;
  const size_t m0 = (size_t)ry * 128, n0 = (size_t)cy * 128;
  const int nk = K >> 6;

  // staging: wave wv stages rows [wv*32, wv*32+32) of A and B tiles
  const int rbase = wv * 32;
  const int lr = lane >> 3;           // row within 8-row chunk
  const int lc = (lane & 7) * 8;      // element col within 64

  auto stage = [&](int kt){
    int kc = kt * 64 + lc;
    #pragma unroll
    for (int i = 0; i < 4; ++i){
      int rr = rbase + i * 8;
      gload_lds16(Ab + (m0 + rr + lr) * (size_t)K + kc, As + rr * 64);
      gload_lds16(Bt + (n0 + rr + lr) * (size_t)K + kc, Bs + rr * 64);
    }
  };

  f32x4 acc[4][4] = {};
  stage(0);
  #pragma unroll 1
  for (int kt = 0; kt < nk; ++kt){
    __syncthreads();                 // drains vmcnt: tile resident
    #pragma unroll
    for (int ks = 0; ks < 2; ++ks){
      short8 a[4], b[4];
      #pragma unroll
      for (int mi = 0; mi < 4; ++mi)
        a[mi] = *(const short8*)(As + (wr*64 + mi*16 + l16) * 64 + ks*32 + lk*8);
      #pragma unroll
      for (int ni = 0; ni < 4; ++ni)
        b[ni] = *(const short8*)(Bs + (wc*64 + ni*16 + l16) * 64 + ks*32 + lk*8);
      #pragma unroll
      for (int mi = 0; mi < 4; ++mi)
        #pragma unroll
        for (int ni = 0; ni < 4; ++ni)
          acc[mi][ni] = __builtin_amdgcn_mfma_f32_16x16x32_bf16(a[mi], b[ni], acc[mi][ni], 0, 0, 0);
    }
    __syncthreads();                 // all waves done reading LDS
    if (kt + 1 < nk) stage(kt + 1);
  }

  const int rowb = (int)m0 + wr*64;
  const int colb = (int)n0 + wc*64;
  #pragma unroll
  for (int ni = 0; ni < 4; ++ni){
    int ccol = colb + ni*16 + l16;
    float bs = bias[ccol];
    #pragma unroll
    for (int mi = 0; mi < 4; ++mi){
      #pragma unroll
      for (int i = 0; i < 4; ++i){
        int r = rowb + mi*16 + lk*4 + i;
        float v = acc[mi][ni][i] + bs;
        if constexpr (MODE == 0){
          int t3 = ccol >> 10, rem2 = ccol & 1023, h = rem2 >> 6, cc = rem2 & 63;
          int b = r / 196;
          int n = r - b * 196;
          int bhh = h * 64 + b;
          u16 bv = f2bf(v);
          if (t3 == 0)      qg[((size_t)bhh * SP + n) * HD + cc] = bv;
          else if (t3 == 1) kg[((size_t)bhh * SP + n) * HD + cc] = bv;
          else              vTg[((size_t)bhh * HD + cc) * SPV + n] = bv;
        } else {
          outf[(size_t)r * N + ccol] = v;
        }
      }
    }
  }
}

// ---- fused attention: one WAVE per (bh, q-tile) job; 4 waves/block ----
__global__ __launch_bounds__(256) void k_attn(
    const u16* __restrict__ qg, const u16* __restrict__ kg, const u16* __restrict__ vTg,
    const float* __restrict__ rph, const float* __restrict__ rpw,
    u16* __restrict__ ao)
{
  __shared__ __align__(16) char smem[4 * 8960];
  const int tid = threadIdx.x, lane = tid & 63, wvi = tid >> 6;
  const int l16 = lane & 15, lk = lane >> 4;
  char*  pbase = smem + wvi * 8960;            // 16 x 224 bf16, swizzled cols<384B
  float* relf  = (float*)(pbase + 7168);       // [16][28] f32

  // XCD-chunked job assignment: 416 consecutive blocks per XCD -> bh-local L2 reuse
  int b = blockIdx.x;
  int sb = (b & 7) * 416 + (b >> 3);
  int j  = sb * 4 + wvi;
  int bh = j / 13;
  int mt = j - bh * 13;
  const int hh = bh >> 6, bb = bh & 63;
  const u16* qb = qg  + (size_t)bh * SP * HD;
  const u16* kb = kg  + (size_t)bh * SP * HD;
  const u16* vb = vTg + (size_t)bh * HD * SPV;

  // ---- rel-pos phase: lane (l16=row, lk) computes 7 of 28 dot products for its row ----
  {
    int qrow = mt*16 + l16;
    int qrc = qrow > HW-1 ? HW-1 : qrow;
    int qh = qrc / 14, qw = qrc - qh * 14;
    short8 qv[8];
    #pragma unroll
    for (int v = 0; v < 8; ++v) qv[v] = *(const short8*)(qb + (size_t)qrow * HD + v * 8);
    f32x2 qf[32];
    #pragma unroll
    for (int v = 0; v < 8; ++v)
      #pragma unroll
      for (int e = 0; e < 4; ++e){
        f32x2 t; t[0] = bf2f((u16)qv[v][2*e]); t[1] = bf2f((u16)qv[v][2*e+1]);
        qf[v*4 + e] = t;
      }
    #pragma unroll
    for (int c = 0; c < 7; ++c){
      int col = lk * 7 + c;
      const float* R = (col < 14) ? (rph + (size_t)(qh - col + 13) * HD)
                                  : (rpw + (size_t)(qw - (col - 14) + 13) * HD);
      f32x2 a2 = {0.f, 0.f};
      #pragma unroll
      for (int p = 0; p < 32; ++p){
        f32x2 rr = *(const f32x2*)(R + p * 2);
        a2 += qf[p] * rr;
      }
      relf[l16 * 28 + col] = a2[0] + a2[1];
    }
  }
  __syncthreads();

  // ---- QK^T: B-fragments straight from global (L2-resident K) ----
  f32x4 z = {0.f, 0.f, 0.f, 0.f};
  f32x4 sacc[13];
  #pragma unroll
  for (int nt = 0; nt < 13; ++nt) sacc[nt] = z;
  const short8 a0 = *(const short8*)(qb + (size_t)(mt*16 + l16) * HD + lk*8);
  const short8 a1 = *(const short8*)(qb + (size_t)(mt*16 + l16) * HD + 32 + lk*8);
  #pragma unroll
  for (int nt = 0; nt < 13; ++nt){
    int row = nt*16 + l16; if (row > HW-1) row = HW-1;
    short8 b0 = *(const short8*)(kb + (size_t)row * HD + lk*8);
    short8 b1 = *(const short8*)(kb + (size_t)row * HD + 32 + lk*8);
    sacc[nt] = __builtin_amdgcn_mfma_f32_16x16x32_bf16(a0, b0, sacc[nt], 0, 0, 0);
    sacc[nt] = __builtin_amdgcn_mfma_f32_16x16x32_bf16(a1, b1, sacc[nt], 0, 0, 0);
  }

  // ---- scale + rel bias + key mask ----
  #pragma unroll
  for (int nt = 0; nt < 13; ++nt){
    int key = nt*16 + l16;
    int kh = key / 14, kw = key - kh*14;
    bool kok = key < HW;
    #pragma unroll
    for (int i = 0; i < 4; ++i){
      int rloc = lk*4 + i;
      float s;
      if (!kok) s = -1e30f;
      else      s = sacc[nt][i] * 0.125f + relf[rloc*28 + kh] + relf[rloc*28 + 14 + kw];
      sacc[nt][i] = s;
    }
  }

  // ---- softmax over 196 keys ----
  #pragma unroll
  for (int i = 0; i < 4; ++i){
    float m = -1e30f;
    #pragma unroll
    for (int nt = 0; nt < 13; ++nt) m = fmaxf(m, sacc[nt][i]);
    #pragma unroll
    for (int d = 1; d < 16; d <<= 1) m = fmaxf(m, __shfl_xor(m, d, 64));
    float sum = 0.f;
    #pragma unroll
    for (int nt = 0; nt < 13; ++nt){
      float p = __expf(sacc[nt][i] - m);
      sacc[nt][i] = p; sum += p;
    }
    #pragma unroll
    for (int d = 1; d < 16; d <<= 1) sum += __shfl_xor(sum, d, 64);
    float inv = 1.f / sum;
    #pragma unroll
    for (int nt = 0; nt < 13; ++nt) sacc[nt][i] *= inv;
  }

  // ---- stage P (bf16) into per-wave LDS, swizzled for cols < 384 B ----
  #pragma unroll
  for (int nt = 0; nt < 14; ++nt){
    #pragma unroll
    for (int i = 0; i < 4; ++i){
      int prow = lk*4 + i;
      int key = nt*16 + l16;
      float pv = (nt < 13) ? sacc[nt][i] : 0.f;
      if (key >= HW || mt*16 + prow >= HW) pv = 0.f;
      int c2 = key * 2;
      if (nt < 12) c2 ^= (prow & 7) << 4;
      *(u16*)(pbase + prow*448 + c2) = f2bf(pv);
    }
  }
  asm volatile("s_waitcnt lgkmcnt(0)" ::: "memory");
  __builtin_amdgcn_sched_barrier(0);

  // ---- PV: P from LDS (A-frag), V^T from global (B-frag) ----
  f32x4 oacc[4];
  #pragma unroll
  for (int n = 0; n < 4; ++n) oacc[n] = z;
  #pragma unroll
  for (int kt = 0; kt < 7; ++kt){
    int c2 = kt*64 + lk*16;
    if (kt < 6) c2 ^= (l16 & 7) << 4;
    short8 pa = *(const short8*)(pbase + l16*448 + c2);
    #pragma unroll
    for (int n = 0; n < 4; ++n){
      short8 bv = *(const short8*)(vb + (size_t)(n*16 + l16) * SPV + kt*32 + lk*8);
      oacc[n] = __builtin_amdgcn_mfma_f32_16x16x32_bf16(pa, bv, oacc[n], 0, 0, 0);
    }
  }
  #pragma unroll
  for (int n = 0; n < 4; ++n){
    int cc = n*16 + l16;
    #pragma unroll
    for (int i = 0; i < 4; ++i){
      int qrow = mt*16 + lk*4 + i;
      if (qrow < HW)
        ao[((size_t)bb * HW + qrow) * DIM + hh * HD + cc] = f2bf(oacc[n][i]);
    }
  }
}

extern "C" void kernel_launch(void* const* d_in, const int* in_sizes, int n_in,
                              void* d_out, int out_size, void* d_ws, size_t ws_size,
                              hipStream_t stream)
{
  const float* x      = (const float*)d_in[0];
  const float* qkv_w  = (const float*)d_in[1];
  const float* qkv_b  = (const float*)d_in[2];
  const float* proj_w = (const float*)d_in[3];
  const float* proj_b = (const float*)d_in[4];
  const float* rph    = (const float*)d_in[5];
  const float* rpw    = (const float*)d_in[6];
  float* out = (float*)d_out;
  char* ws = (char*)d_ws;

  size_t off = 0;
  auto alloc = [&](size_t b){ size_t r = off; off += (b + 255) & ~(size_t)255; return r; };
  u16* wqkvT = (u16*)(ws + alloc((size_t)3072*1024*2));
  u16* wprojT= (u16*)(ws + alloc((size_t)1024*1024*2));
  u16* qg    = (u16*)(ws + alloc((size_t)NBH*SP*HD*2));
  u16* kg    = (u16*)(ws + alloc((size_t)NBH*SP*HD*2));
  u16* vTg   = (u16*)(ws + alloc((size_t)NBH*HD*SPV*2));
  u16* xb    = (u16*)(ws + alloc((size_t)12544*1024*2));  // aliased: x bf16, then attn out
  u16* ao    = xb;   // disjoint lifetimes: xb dead after k_gemm<0>, ao born at k_attn

  hipMemsetAsync(vTg, 0, (size_t)NBH*HD*SPV*2, stream);

  k_xcvt<<<(12544*1024/8 + 255)/256, 256, 0, stream>>>(x, xb, 12544*1024/8);
  k_wT<<<dim3(96, 32), 256, 0, stream>>>(qkv_w, wqkvT, 1024, 3072);
  k_wT<<<dim3(32, 32), 256, 0, stream>>>(proj_w, wprojT, 1024, 1024);
  k_gemm<0><<<98*24, 256, 0, stream>>>(xb, wqkvT, qkv_b, qg, kg, vTg, nullptr, 1024, 3072, 98, 24);
  k_attn<<<3328, 256, 0, stream>>>(qg, kg, vTg, rph, rpw, ao);
  k_gemm<1><<<98*8, 256, 0, stream>>>(ao, wprojT, proj_b, nullptr, nullptr, nullptr, out, 1024, 1024, 98, 8);
}

// Round 4
// 312.393 us; speedup vs baseline: 1.6424x; 1.3251x over previous
//
#include <hip/hip_runtime.h>
#include <cstdint>
#include <cstddef>

typedef unsigned short u16;
typedef unsigned int u32;
typedef float f32x4 __attribute__((ext_vector_type(4)));
typedef float f32x2 __attribute__((ext_vector_type(2)));
typedef short short8 __attribute__((ext_vector_type(8)));

#define HW 196
#define DIM 1024
#define HD 64
#define SP 208
#define SPV 224
#define NBH 1024

__device__ __forceinline__ float bf2f(u16 x){
  union { u32 u; float f; } c; c.u = ((u32)x) << 16; return c.f;
}
__device__ __forceinline__ u16 f2bf(float f){
  union { float f; u32 u; } c; c.f = f;
  return (u16)((c.u + 0x7fffu + ((c.u >> 16) & 1u)) >> 16);
}
__device__ __forceinline__ u32 cvtpk_bf16(float lo, float hi){
  u32 r;
  asm("v_cvt_pk_bf16_f32 %0, %1, %2" : "=v"(r) : "v"(lo), "v"(hi));
  return r;
}
#define LGKM_FENCE() do { \
    asm volatile("s_waitcnt lgkmcnt(0)" ::: "memory"); \
    __builtin_amdgcn_sched_barrier(0); \
  } while (0)

typedef __attribute__((address_space(3))) void lds_void_t;
typedef __attribute__((address_space(1))) const void glb_void_t;
__device__ __forceinline__ void gload_lds16(const void* g, void* l){
  __builtin_amdgcn_global_load_lds((glb_void_t*)g, (lds_void_t*)l, 16, 0, 0);
}

// ---- x f32 -> bf16 convert ----
__global__ __launch_bounds__(256) void k_xcvt(const float* __restrict__ x,
                                              u16* __restrict__ xb, int n8){
  int i = blockIdx.x * 256 + threadIdx.x;
  if (i < n8){
    const f32x4* p = (const f32x4*)(x + (size_t)i * 8);
    f32x4 v0 = p[0], v1 = p[1];
    short8 t;
    #pragma unroll
    for (int e = 0; e < 4; ++e){
      t[e]   = (short)f2bf(v0[e]);
      t[4+e] = (short)f2bf(v1[e]);
    }
    *(short8*)(xb + (size_t)i * 8) = t;
  }
}

// ---- rel-pos tables f32[27][64] -> bf16[32][64], pad rows zero ----
__global__ __launch_bounds__(256) void k_rprep(const float* __restrict__ rph,
                                               const float* __restrict__ rpw,
                                               u16* __restrict__ rphb,
                                               u16* __restrict__ rpwb){
  int r = threadIdx.x >> 3, cc = (threadIdx.x & 7) * 8;
  #pragma unroll
  for (int t = 0; t < 2; ++t){
    const float* src = t ? rpw : rph;
    u16* dst = t ? rpwb : rphb;
    short8 v;
    #pragma unroll
    for (int e = 0; e < 8; ++e)
      v[e] = (r < 27) ? (short)f2bf(src[(size_t)r * 64 + cc + e]) : (short)0;
    *(short8*)(dst + (size_t)r * 64 + cc) = v;
  }
}

// ---- weight transpose + convert: w[K][N] f32 -> wT[N][K] bf16 ----
__global__ __launch_bounds__(256) void k_wT(const float* __restrict__ w,
                                            u16* __restrict__ wT, int K, int N){
  __shared__ float t[32][33];
  int n0 = blockIdx.x * 32, k0 = blockIdx.y * 32;
  int c = threadIdx.x & 31, rr = threadIdx.x >> 5;
  #pragma unroll
  for (int i = 0; i < 4; ++i){
    int r = rr + i*8;
    t[r][c] = w[(size_t)(k0 + r) * N + n0 + c];
  }
  __syncthreads();
  #pragma unroll
  for (int i = 0; i < 4; ++i){
    int r = rr + i*8;
    wT[(size_t)(n0 + r) * K + k0 + c] = f2bf(t[c][r]);
  }
}

// ---- GEMM (m97 structure) — unchanged from R3 ----
template<int MODE>
__global__ __launch_bounds__(256) void k_gemm(const u16* __restrict__ Ab,
    const u16* __restrict__ Bt, const float* __restrict__ bias,
    u16* __restrict__ qg, u16* __restrict__ kg, u16* __restrict__ vTg,
    float* __restrict__ outf, int K, int N, int ntm, int ntn)
{
  __shared__ __align__(16) u16 As[128*64];
  __shared__ __align__(16) u16 Bs[128*64];
  const int tid = threadIdx.x;
  const int lane = tid & 63, wv = tid >> 6, wr = wv >> 1, wc = wv & 1;
  const int l16 = lane & 15, lk = lane >> 4;

  const int nwg = ntm * ntn;
  int bid = blockIdx.x;
  int q8 = nwg >> 3, r8 = nwg & 7;
  int xcd = bid & 7, loc = bid >> 3;
  int wgid = (xcd < r8 ? xcd*(q8+1) : r8*(q8+1) + (xcd - r8)*q8) + loc;
  int gsz = 8 * ntn;
  int g = wgid / gsz, rem = wgid - g * gsz;
  int gm = ntm - g * 8; if (gm > 8) gm = 8;
  int ry = g * 8 + rem % gm;
  int cy = rem / gm;
  const size_t m0 = (size_t)ry * 128, n0 = (size_t)cy * 128;
  const int nk = K >> 6;

  const int rbase = wv * 32;
  const int lr = lane >> 3;
  const int lc = (lane & 7) * 8;

  auto stage = [&](int kt){
    int kc = kt * 64 + lc;
    #pragma unroll
    for (int i = 0; i < 4; ++i){
      int rr = rbase + i * 8;
      gload_lds16(Ab + (m0 + rr + lr) * (size_t)K + kc, As + rr * 64);
      gload_lds16(Bt + (n0 + rr + lr) * (size_t)K + kc, Bs + rr * 64);
    }
  };

  f32x4 acc[4][4] = {};
  stage(0);
  #pragma unroll 1
  for (int kt = 0; kt < nk; ++kt){
    __syncthreads();
    #pragma unroll
    for (int ks = 0; ks < 2; ++ks){
      short8 a[4], b[4];
      #pragma unroll
      for (int mi = 0; mi < 4; ++mi)
        a[mi] = *(const short8*)(As + (wr*64 + mi*16 + l16) * 64 + ks*32 + lk*8);
      #pragma unroll
      for (int ni = 0; ni < 4; ++ni)
        b[ni] = *(const short8*)(Bs + (wc*64 + ni*16 + l16) * 64 + ks*32 + lk*8);
      #pragma unroll
      for (int mi = 0; mi < 4; ++mi)
        #pragma unroll
        for (int ni = 0; ni < 4; ++ni)
          acc[mi][ni] = __builtin_amdgcn_mfma_f32_16x16x32_bf16(a[mi], b[ni], acc[mi][ni], 0, 0, 0);
    }
    __syncthreads();
    if (kt + 1 < nk) stage(kt + 1);
  }

  const int rowb = (int)m0 + wr*64;
  const int colb = (int)n0 + wc*64;
  #pragma unroll
  for (int ni = 0; ni < 4; ++ni){
    int ccol = colb + ni*16 + l16;
    float bs = bias[ccol];
    #pragma unroll
    for (int mi = 0; mi < 4; ++mi){
      #pragma unroll
      for (int i = 0; i < 4; ++i){
        int r = rowb + mi*16 + lk*4 + i;
        float v = acc[mi][ni][i] + bs;
        if constexpr (MODE == 0){
          int t3 = ccol >> 10, rem2 = ccol & 1023, h = rem2 >> 6, cc = rem2 & 63;
          int b = r / 196;
          int n = r - b * 196;
          int bhh = h * 64 + b;
          u16 bv = f2bf(v);
          if (t3 == 0)      qg[((size_t)bhh * SP + n) * HD + cc] = bv;
          else if (t3 == 1) kg[((size_t)bhh * SP + n) * HD + cc] = bv;
          else              vTg[((size_t)bhh * HD + cc) * SPV + n] = bv;
        } else {
          outf[(size_t)r * N + ccol] = v;
        }
      }
    }
  }
}

// ---- fused attention: one WAVE per (bh, q-tile); rel via MFMA; no block barriers ----
// per-wave LDS 7168B: relT[16][65]f32 @0 (4160), relg[16][29]f32 @4160 (1856),
// P[16][224]bf16 @0 (7168, written after relT/relg are dead).
__global__ __launch_bounds__(256) void k_attn(
    const u16* __restrict__ qg, const u16* __restrict__ kg, const u16* __restrict__ vTg,
    const u16* __restrict__ rphb, const u16* __restrict__ rpwb,
    u16* __restrict__ ao)
{
  __shared__ __align__(16) char smem[4 * 7168];
  const int tid = threadIdx.x, lane = tid & 63, wvi = tid >> 6;
  const int l16 = lane & 15, lk = lane >> 4;
  char*  wbase = smem + wvi * 7168;
  float* relT  = (float*)wbase;            // [16][65] f32
  float* relg  = (float*)(wbase + 4160);   // [16][29] f32
  char*  pbase = wbase;                    // [16][224] bf16 (post-bias)

  int b = blockIdx.x;
  int sb = (b & 7) * 416 + (b >> 3);
  int j  = sb * 4 + wvi;
  int bh = j / 13;
  int mt = j - bh * 13;
  const int hh = bh >> 6, bb = bh & 63;
  const u16* qb = qg  + (size_t)bh * SP * HD;
  const u16* kb = kg  + (size_t)bh * SP * HD;
  const u16* vb = vTg + (size_t)bh * HD * SPV;

  // ---- Q fragment (A-frag for QK, B-frag for rel MFMAs) ----
  const short8 a0 = *(const short8*)(qb + (size_t)(mt*16 + l16) * HD + lk*8);
  const short8 a1 = *(const short8*)(qb + (size_t)(mt*16 + l16) * HD + 32 + lk*8);

  // ---- rel tables via MFMA: T[delta][q] = Rb[delta] . Q[q] ----
  {
    f32x4 z = {0.f,0.f,0.f,0.f};
    f32x4 racc[2][2] = {{z,z},{z,z}};   // [table][delta-tile]
    #pragma unroll
    for (int dt = 0; dt < 2; ++dt){
      short8 h0 = *(const short8*)(rphb + (size_t)(dt*16 + l16) * 64 + lk*8);
      short8 h1 = *(const short8*)(rphb + (size_t)(dt*16 + l16) * 64 + 32 + lk*8);
      short8 w0 = *(const short8*)(rpwb + (size_t)(dt*16 + l16) * 64 + lk*8);
      short8 w1 = *(const short8*)(rpwb + (size_t)(dt*16 + l16) * 64 + 32 + lk*8);
      racc[0][dt] = __builtin_amdgcn_mfma_f32_16x16x32_bf16(h0, a0, racc[0][dt], 0, 0, 0);
      racc[0][dt] = __builtin_amdgcn_mfma_f32_16x16x32_bf16(h1, a1, racc[0][dt], 0, 0, 0);
      racc[1][dt] = __builtin_amdgcn_mfma_f32_16x16x32_bf16(w0, a0, racc[1][dt], 0, 0, 0);
      racc[1][dt] = __builtin_amdgcn_mfma_f32_16x16x32_bf16(w1, a1, racc[1][dt], 0, 0, 0);
    }
    #pragma unroll
    for (int t = 0; t < 2; ++t)
      #pragma unroll
      for (int dt = 0; dt < 2; ++dt)
        #pragma unroll
        for (int i = 0; i < 4; ++i)
          relT[l16*65 + t*32 + dt*16 + lk*4 + i] = racc[t][dt][i];
  }
  LGKM_FENCE();

  // ---- gather T -> relg[q][j]: j<14 -> Th[qh+13-j], else Tw[qw+13-(j-14)] ----
  {
    int qr = mt*16 + l16;
    int qh = qr / 14, qw = qr - 14*qh;
    #pragma unroll
    for (int c = 0; c < 7; ++c){
      int jj = lk*7 + c;
      int ah = l16*65 + (qh + 13 - jj);
      int aw = l16*65 + 32 + (qw + 27 - jj);
      float v = relT[(jj < 14) ? ah : aw];
      relg[l16*29 + jj] = v;
    }
  }
  LGKM_FENCE();

  // ---- QK^T ----
  f32x4 z = {0.f, 0.f, 0.f, 0.f};
  f32x4 sacc[13];
  #pragma unroll
  for (int nt = 0; nt < 13; ++nt) sacc[nt] = z;
  #pragma unroll
  for (int nt = 0; nt < 13; ++nt){
    int row = nt*16 + l16;
    short8 b0 = *(const short8*)(kb + (size_t)row * HD + lk*8);
    short8 b1 = *(const short8*)(kb + (size_t)row * HD + 32 + lk*8);
    sacc[nt] = __builtin_amdgcn_mfma_f32_16x16x32_bf16(a0, b0, sacc[nt], 0, 0, 0);
    sacc[nt] = __builtin_amdgcn_mfma_f32_16x16x32_bf16(a1, b1, sacc[nt], 0, 0, 0);
  }

  // ---- scale + rel bias + key mask ----
  #pragma unroll
  for (int nt = 0; nt < 13; ++nt){
    int key = nt*16 + l16;
    int kh = key / 14, kw = key - 14*kh;   // kh may be 14 for pad keys (masked)
    bool kok = key < HW;
    #pragma unroll
    for (int i = 0; i < 4; ++i){
      int rl = lk*4 + i;
      float s = sacc[nt][i] * 0.125f + relg[rl*29 + kh] + relg[rl*29 + 14 + kw];
      sacc[nt][i] = kok ? s : -1e30f;
    }
  }

  // ---- softmax over 196 keys ----
  #pragma unroll
  for (int i = 0; i < 4; ++i){
    float m = -1e30f;
    #pragma unroll
    for (int nt = 0; nt < 13; ++nt) m = fmaxf(m, sacc[nt][i]);
    #pragma unroll
    for (int d = 1; d < 16; d <<= 1) m = fmaxf(m, __shfl_xor(m, d, 64));
    float sum = 0.f;
    #pragma unroll
    for (int nt = 0; nt < 13; ++nt){
      float p = __expf(sacc[nt][i] - m);
      sacc[nt][i] = p; sum += p;
    }
    #pragma unroll
    for (int d = 1; d < 16; d <<= 1) sum += __shfl_xor(sum, d, 64);
    float inv = 1.f / sum;
    #pragma unroll
    for (int nt = 0; nt < 13; ++nt) sacc[nt][i] *= inv;
  }

  // ---- stage P (bf16) into per-wave LDS (aliases relT/relg: both dead) ----
  #pragma unroll
  for (int nt = 0; nt < 14; ++nt){
    #pragma unroll
    for (int i = 0; i < 4; ++i){
      int prow = lk*4 + i;
      int key = nt*16 + l16;
      float pv = (nt < 13) ? sacc[nt][i] : 0.f;
      if (key >= HW || mt*16 + prow >= HW) pv = 0.f;
      int c2 = key * 2;
      if (nt < 12) c2 ^= (prow & 7) << 4;
      *(u16*)(pbase + prow*448 + c2) = f2bf(pv);
    }
  }
  LGKM_FENCE();

  // ---- PV (swapped): O^T tiles; C gives O[q=l16][d=16dt+lk*4+i] ----
  f32x4 oacc[4];
  #pragma unroll
  for (int n = 0; n < 4; ++n) oacc[n] = z;
  #pragma unroll
  for (int kt = 0; kt < 7; ++kt){
    int c2 = kt*64 + lk*16;
    if (kt < 6) c2 ^= (l16 & 7) << 4;
    short8 pa = *(const short8*)(pbase + l16*448 + c2);
    #pragma unroll
    for (int dt = 0; dt < 4; ++dt){
      short8 bv = *(const short8*)(vb + (size_t)(dt*16 + l16) * SPV + kt*32 + lk*8);
      oacc[dt] = __builtin_amdgcn_mfma_f32_16x16x32_bf16(bv, pa, oacc[dt], 0, 0, 0);
    }
  }
  int qrow = mt*16 + l16;
  if (qrow < HW){
    u16* orow = ao + ((size_t)bb * HW + qrow) * DIM + hh * HD;
    #pragma unroll
    for (int dt = 0; dt < 4; ++dt){
      u32 lo = cvtpk_bf16(oacc[dt][0], oacc[dt][1]);
      u32 hi = cvtpk_bf16(oacc[dt][2], oacc[dt][3]);
      u32* dst = (u32*)(orow + dt*16 + lk*4);
      dst[0] = lo; dst[1] = hi;
    }
  }
}

extern "C" void kernel_launch(void* const* d_in, const int* in_sizes, int n_in,
                              void* d_out, int out_size, void* d_ws, size_t ws_size,
                              hipStream_t stream)
{
  const float* x      = (const float*)d_in[0];
  const float* qkv_w  = (const float*)d_in[1];
  const float* qkv_b  = (const float*)d_in[2];
  const float* proj_w = (const float*)d_in[3];
  const float* proj_b = (const float*)d_in[4];
  const float* rph    = (const float*)d_in[5];
  const float* rpw    = (const float*)d_in[6];
  float* out = (float*)d_out;
  char* ws = (char*)d_ws;

  size_t off = 0;
  auto alloc = [&](size_t b){ size_t r = off; off += (b + 255) & ~(size_t)255; return r; };
  u16* wqkvT = (u16*)(ws + alloc((size_t)3072*1024*2));
  u16* wprojT= (u16*)(ws + alloc((size_t)1024*1024*2));
  u16* qg    = (u16*)(ws + alloc((size_t)NBH*SP*HD*2));
  u16* kg    = (u16*)(ws + alloc((size_t)NBH*SP*HD*2));
  u16* vTg   = (u16*)(ws + alloc((size_t)NBH*HD*SPV*2));
  u16* rphb  = (u16*)(ws + alloc((size_t)32*64*2));
  u16* rpwb  = (u16*)(ws + alloc((size_t)32*64*2));
  u16* xb    = (u16*)(ws + alloc((size_t)12544*1024*2));
  u16* ao    = xb;   // disjoint lifetimes

  hipMemsetAsync(vTg, 0, (size_t)NBH*HD*SPV*2, stream);

  k_xcvt<<<(12544*1024/8 + 255)/256, 256, 0, stream>>>(x, xb, 12544*1024/8);
  k_wT<<<dim3(96, 32), 256, 0, stream>>>(qkv_w, wqkvT, 1024, 3072);
  k_wT<<<dim3(32, 32), 256, 0, stream>>>(proj_w, wprojT, 1024, 1024);
  k_rprep<<<1, 256, 0, stream>>>(rph, rpw, rphb, rpwb);
  k_gemm<0><<<98*24, 256, 0, stream>>>(xb, wqkvT, qkv_b, qg, kg, vTg, nullptr, 1024, 3072, 98, 24);
  k_attn<<<3328, 256, 0, stream>>>(qg, kg, vTg, rphb, rpwb, ao);
  k_gemm<1><<<98*8, 256, 0, stream>>>(ao, wprojT, proj_b, nullptr, nullptr, nullptr, out, 1024, 1024, 98, 8);
}

// Round 6
// 260.222 us; speedup vs baseline: 1.9717x; 1.2005x over previous
//
#include <hip/hip_runtime.h>
#include <cstdint>
#include <cstddef>

typedef unsigned short u16;
typedef unsigned int u32;
typedef float f32x4 __attribute__((ext_vector_type(4)));
typedef float f32x2 __attribute__((ext_vector_type(2)));
typedef short short8 __attribute__((ext_vector_type(8)));

#define HW 196
#define DIM 1024
#define HD 64
#define SP 208
#define SPV 224
#define NBH 1024

__device__ __forceinline__ float bf2f(u16 x){
  union { u32 u; float f; } c; c.u = ((u32)x) << 16; return c.f;
}
__device__ __forceinline__ u16 f2bf(float f){
  union { float f; u32 u; } c; c.f = f;
  return (u16)((c.u + 0x7fffu + ((c.u >> 16) & 1u)) >> 16);
}
__device__ __forceinline__ u32 cvtpk_bf16(float lo, float hi){
  u32 r;
  asm("v_cvt_pk_bf16_f32 %0, %1, %2" : "=v"(r) : "v"(lo), "v"(hi));
  return r;
}
#define LGKM_FENCE() do { \
    asm volatile("s_waitcnt lgkmcnt(0)" ::: "memory"); \
    __builtin_amdgcn_sched_barrier(0); \
  } while (0)
#define WAITV4() asm volatile("s_waitcnt vmcnt(4)" ::: "memory")
#define BAR() __builtin_amdgcn_s_barrier()

typedef __attribute__((address_space(3))) void lds_void_t;
typedef __attribute__((address_space(1))) const void glb_void_t;
__device__ __forceinline__ void gload_lds16(const void* g, void* l){
  __builtin_amdgcn_global_load_lds((glb_void_t*)g, (lds_void_t*)l, 16, 0, 0);
}

// ---- x f32 -> bf16 convert ----
__global__ __launch_bounds__(256) void k_xcvt(const float* __restrict__ x,
                                              u16* __restrict__ xb, int n8){
  int i = blockIdx.x * 256 + threadIdx.x;
  if (i < n8){
    const f32x4* p = (const f32x4*)(x + (size_t)i * 8);
    f32x4 v0 = p[0], v1 = p[1];
    short8 t;
    #pragma unroll
    for (int e = 0; e < 4; ++e){
      t[e]   = (short)f2bf(v0[e]);
      t[4+e] = (short)f2bf(v1[e]);
    }
    *(short8*)(xb + (size_t)i * 8) = t;
  }
}

// ---- rel-pos tables f32[27][64] -> bf16[32][64], pad rows zero ----
__global__ __launch_bounds__(256) void k_rprep(const float* __restrict__ rph,
                                               const float* __restrict__ rpw,
                                               u16* __restrict__ rphb,
                                               u16* __restrict__ rpwb){
  int r = threadIdx.x >> 3, cc = (threadIdx.x & 7) * 8;
  #pragma unroll
  for (int t = 0; t < 2; ++t){
    const float* src = t ? rpw : rph;
    u16* dst = t ? rpwb : rphb;
    short8 v;
    #pragma unroll
    for (int e = 0; e < 8; ++e)
      v[e] = (r < 27) ? (short)f2bf(src[(size_t)r * 64 + cc + e]) : (short)0;
    *(short8*)(dst + (size_t)r * 64 + cc) = v;
  }
}

// ---- weight transpose + convert: w[K][N] f32 -> wT[N][K] bf16 ----
__global__ __launch_bounds__(256) void k_wT(const float* __restrict__ w,
                                            u16* __restrict__ wT, int K, int N){
  __shared__ float t[32][33];
  int n0 = blockIdx.x * 32, k0 = blockIdx.y * 32;
  int c = threadIdx.x & 31, rr = threadIdx.x >> 5;
  #pragma unroll
  for (int i = 0; i < 4; ++i){
    int r = rr + i*8;
    t[r][c] = w[(size_t)(k0 + r) * N + n0 + c];
  }
  __syncthreads();
  #pragma unroll
  for (int i = 0; i < 4; ++i){
    int r = rr + i*8;
    wT[(size_t)(n0 + r) * K + k0 + c] = f2bf(t[c][r]);
  }
}

// ================= 256x256 8-phase GEMM (T2+T3+T4+T5) =================
// C[256ry][256cy] = A[M][K](bf16) * Bt[N][K]^T + bias.
// 8 waves (2M x 4N), BK=64 staged as two K-32 halves, 2 LDS dbuf (128 KiB).
// Counted vmcnt(4) waits sit BEFORE the barrier preceding the dependent
// ds_reads (phase1 guards {A1,B1}(t); phase3 guards {A0,B0}(t+1)); loads
// never drain below 4 outstanding.
// SW: operand-swapped MFMA (C^T fragments) -> column-contiguous epilogue.
template<int MODE, bool SW>
__global__ __launch_bounds__(512, 2) void k_g256(const u16* __restrict__ Ab,
    const u16* __restrict__ Bt, const float* __restrict__ bias,
    u16* __restrict__ qg, u16* __restrict__ kg, u16* __restrict__ vTg,
    float* __restrict__ outf, int K, int N, int ntm, int ntn, int cyoff)
{
  extern __shared__ __align__(16) u16 smem[];   // [d][ab][ks][256][32] = 128 KiB
  const int tid = threadIdx.x;
  const int lane = tid & 63, wv = tid >> 6;
  const int wr = wv >> 2, wc = wv & 3;
  const int l16 = lane & 15, lk = lane >> 4;

  // bijective XCD chunking over GROUP_M=8 serpentine
  const int nwg = ntm * ntn;
  int bid = blockIdx.x;
  int q8 = nwg >> 3, r8 = nwg & 7;
  int xcd = bid & 7, loc = bid >> 3;
  int wgid = (xcd < r8 ? xcd*(q8+1) : r8*(q8+1) + (xcd - r8)*q8) + loc;
  int gsz = 8 * ntn;
  int g = wgid / gsz, rem = wgid - g * gsz;
  int gm = ntm - g * 8; if (gm > 8) gm = 8;
  int ry = g * 8 + rem % gm;
  int cy = rem / gm;
  const size_t m0 = (size_t)ry * 256;
  const size_t n0 = (size_t)(cyoff + cy) * 256;
  const int nk = K >> 6;

  // LDS region offset (u16 units): half = 16 KiB = 8192 u16
  auto off = [&](int d, int ab, int ks){ return ((d*2 + ab)*2 + ks) * 8192; };

  // stage one (A|B, ks) half of K-tile `tile` into dbuf d  (2 gload_lds / wave)
  auto stageH = [&](int d, int ab, int ks, int tile){
    const u16* src = ab ? Bt : Ab;
    size_t rb = ab ? n0 : m0;
    int c = (lane & 3) ^ ((lane >> 3) & 3);           // inverse read-swizzle on source
    #pragma unroll
    for (int i = 0; i < 2; ++i){
      int rh = 32*wv + 16*i + (lane >> 2);
      gload_lds16(src + (rb + rh) * (size_t)K + tile*64 + ks*32 + c*8,
                  smem + off(d, ab, ks) + (32*wv + 16*i) * 32);
    }
  };
  // frag loads (swizzled ds_read_b128)
  auto ldA = [&](short8* a, int d, int ks, int h){
    #pragma unroll
    for (int m2 = 0; m2 < 4; ++m2){
      int r = wr*128 + h*64 + m2*16 + l16;
      a[m2] = *(const short8*)(smem + off(d,0,ks) + r*32 + ((lk ^ ((r>>1)&3)) << 3));
    }
  };
  auto ldB = [&](short8* b, int d, int ks){
    #pragma unroll
    for (int ni = 0; ni < 4; ++ni){
      int r = wc*64 + ni*16 + l16;
      b[ni] = *(const short8*)(smem + off(d,1,ks) + r*32 + ((lk ^ ((r>>1)&3)) << 3));
    }
  };

  f32x4 acc[8][4] = {};
  auto mm = [&](int h, short8* a, short8* b){
    __builtin_amdgcn_s_setprio(1);
    #pragma unroll
    for (int m2 = 0; m2 < 4; ++m2)
      #pragma unroll
      for (int ni = 0; ni < 4; ++ni){
        if constexpr (SW)
          acc[h*4+m2][ni] = __builtin_amdgcn_mfma_f32_16x16x32_bf16(b[ni], a[m2], acc[h*4+m2][ni], 0, 0, 0);
        else
          acc[h*4+m2][ni] = __builtin_amdgcn_mfma_f32_16x16x32_bf16(a[m2], b[ni], acc[h*4+m2][ni], 0, 0, 0);
      }
    __builtin_amdgcn_s_setprio(0);
  };

  // prologue: tile 0; guarantee {A0,B0}(0) before the loop's first ds_reads
  stageH(0, 0, 0, 0); stageH(0, 1, 0, 0); stageH(0, 0, 1, 0); stageH(0, 1, 1, 0);
  WAITV4(); BAR();

  #pragma unroll 1
  for (int kt = 0; kt < nk; ++kt){
    const int d = kt & 1, dn = d ^ 1;
    const int tn = (kt + 1 < nk) ? kt + 1 : nk - 1;  // redundant restage keeps wait counts valid
    short8 a[4], b0[4], b1[4];
    // phase 0: (h0, ks0) — {A0,B0}(kt) guaranteed by prev phase-3 wait + BAR
    ldA(a, d, 0, 0); ldB(b0, d, 0);
    stageH(dn, 0, 0, tn);
    BAR(); LGKM_FENCE();
    mm(0, a, b0);
    BAR();
    // phase 1: (h1, ks0) — reuse b0; wait completes {A1,B1}(kt) for phase 2
    ldA(a, d, 0, 1);
    stageH(dn, 1, 0, tn);
    WAITV4();
    BAR(); LGKM_FENCE();
    mm(1, a, b0);
    BAR();
    // phase 2: (h0, ks1)
    ldA(a, d, 1, 0); ldB(b1, d, 1);
    stageH(dn, 0, 1, tn);
    BAR(); LGKM_FENCE();
    mm(0, a, b1);
    BAR();
    // phase 3: (h1, ks1) — wait completes {A0,B0}(kt+1) for next phase 0
    ldA(a, d, 1, 1);
    stageH(dn, 1, 1, tn);
    WAITV4();
    BAR(); LGKM_FENCE();
    mm(1, a, b1);
    BAR();
  }

  const int rowb = (int)m0 + wr*128;
  const int colb = (int)n0 + wc*64;
  if constexpr (MODE == 1){
    // SW layout: value(mi,ni,i): row = rowb+mi*16+l16, col = colb+ni*16+lk*4+i
    #pragma unroll
    for (int mi = 0; mi < 8; ++mi){
      int r = rowb + mi*16 + l16;
      float* orow = outf + (size_t)r * N;
      #pragma unroll
      for (int ni = 0; ni < 4; ++ni){
        int c0 = colb + ni*16 + lk*4;
        f32x4 bz = *(const f32x4*)(bias + c0);
        f32x4 v = acc[mi][ni] + bz;
        *(f32x4*)(orow + c0) = v;
      }
    }
  } else if constexpr (SW){
    // q/k thirds: row-major [bh][n][cc]; lane's 4 vals are consecutive cc
    const int t3 = colb >> 10;
    u16* dst0 = (t3 == 0) ? qg : kg;
    #pragma unroll
    for (int mi = 0; mi < 8; ++mi){
      int r = rowb + mi*16 + l16;
      int b = r / 196, n = r - b * 196;
      #pragma unroll
      for (int ni = 0; ni < 4; ++ni){
        int rr2 = ((colb & 1023) + ni*16);
        int hh = rr2 >> 6, ccb = (rr2 & 63) + lk*4;
        const float* bz = bias + colb + ni*16 + lk*4;
        u32 w0 = cvtpk_bf16(acc[mi][ni][0] + bz[0], acc[mi][ni][1] + bz[1]);
        u32 w1 = cvtpk_bf16(acc[mi][ni][2] + bz[2], acc[mi][ni][3] + bz[3]);
        u32* dst = (u32*)(dst0 + ((size_t)(hh*64 + b) * SP + n) * HD + ccb);
        dst[0] = w0; dst[1] = w1;
      }
    }
  } else {
    // v third: vT [bh][cc][n]; lane's 4 vals are consecutive n
    #pragma unroll
    for (int mi = 0; mi < 8; ++mi){
      int r4 = rowb + mi*16 + lk*4;
      int b = r4 / 196, n4 = r4 - b * 196;
      #pragma unroll
      for (int ni = 0; ni < 4; ++ni){
        int rr2 = ((colb & 1023) + ni*16);
        int hh = rr2 >> 6, cc = (rr2 & 63) + l16;
        float bz = bias[colb + ni*16 + l16];
        u32 w0 = cvtpk_bf16(acc[mi][ni][0] + bz, acc[mi][ni][1] + bz);
        u32 w1 = cvtpk_bf16(acc[mi][ni][2] + bz, acc[mi][ni][3] + bz);
        u32* dst = (u32*)(vTg + ((size_t)(hh*64 + b) * HD + cc) * SPV + n4);
        dst[0] = w0; dst[1] = w1;
      }
    }
  }
}

// ---- fused attention: one WAVE per (bh, q-tile); rel via MFMA; no block barriers ----
__global__ __launch_bounds__(256) void k_attn(
    const u16* __restrict__ qg, const u16* __restrict__ kg, const u16* __restrict__ vTg,
    const u16* __restrict__ rphb, const u16* __restrict__ rpwb,
    u16* __restrict__ ao)
{
  __shared__ __align__(16) char smem[4 * 7168];
  const int tid = threadIdx.x, lane = tid & 63, wvi = tid >> 6;
  const int l16 = lane & 15, lk = lane >> 4;
  char*  wbase = smem + wvi * 7168;
  float* relT  = (float*)wbase;            // [16][65] f32
  float* relg  = (float*)(wbase + 4160);   // [16][29] f32
  char*  pbase = wbase;                    // [16][224] bf16 (post-bias)

  int b = blockIdx.x;
  int sb = (b & 7) * 416 + (b >> 3);
  int j  = sb * 4 + wvi;
  int bh = j / 13;
  int mt = j - bh * 13;
  const int hh = bh >> 6, bb = bh & 63;
  const u16* qb = qg  + (size_t)bh * SP * HD;
  const u16* kb = kg  + (size_t)bh * SP * HD;
  const u16* vb = vTg + (size_t)bh * HD * SPV;

  const short8 a0 = *(const short8*)(qb + (size_t)(mt*16 + l16) * HD + lk*8);
  const short8 a1 = *(const short8*)(qb + (size_t)(mt*16 + l16) * HD + 32 + lk*8);

  // rel tables via MFMA: T[delta][q] = Rb[delta] . Q[q]
  {
    f32x4 z = {0.f,0.f,0.f,0.f};
    f32x4 racc[2][2] = {{z,z},{z,z}};
    #pragma unroll
    for (int dt = 0; dt < 2; ++dt){
      short8 h0 = *(const short8*)(rphb + (size_t)(dt*16 + l16) * 64 + lk*8);
      short8 h1 = *(const short8*)(rphb + (size_t)(dt*16 + l16) * 64 + 32 + lk*8);
      short8 w0 = *(const short8*)(rpwb + (size_t)(dt*16 + l16) * 64 + lk*8);
      short8 w1 = *(const short8*)(rpwb + (size_t)(dt*16 + l16) * 64 + 32 + lk*8);
      racc[0][dt] = __builtin_amdgcn_mfma_f32_16x16x32_bf16(h0, a0, racc[0][dt], 0, 0, 0);
      racc[0][dt] = __builtin_amdgcn_mfma_f32_16x16x32_bf16(h1, a1, racc[0][dt], 0, 0, 0);
      racc[1][dt] = __builtin_amdgcn_mfma_f32_16x16x32_bf16(w0, a0, racc[1][dt], 0, 0, 0);
      racc[1][dt] = __builtin_amdgcn_mfma_f32_16x16x32_bf16(w1, a1, racc[1][dt], 0, 0, 0);
    }
    #pragma unroll
    for (int t = 0; t < 2; ++t)
      #pragma unroll
      for (int dt = 0; dt < 2; ++dt)
        #pragma unroll
        for (int i = 0; i < 4; ++i)
          relT[l16*65 + t*32 + dt*16 + lk*4 + i] = racc[t][dt][i];
  }
  LGKM_FENCE();

  {
    int qr = mt*16 + l16;
    int qh = qr / 14, qw = qr - 14*qh;
    #pragma unroll
    for (int c = 0; c < 7; ++c){
      int jj = lk*7 + c;
      int ah = l16*65 + (qh + 13 - jj);
      int aw = l16*65 + 32 + (qw + 27 - jj);
      float v = relT[(jj < 14) ? ah : aw];
      relg[l16*29 + jj] = v;
    }
  }
  LGKM_FENCE();

  f32x4 z = {0.f, 0.f, 0.f, 0.f};
  f32x4 sacc[13];
  #pragma unroll
  for (int nt = 0; nt < 13; ++nt) sacc[nt] = z;
  #pragma unroll
  for (int nt = 0; nt < 13; ++nt){
    int row = nt*16 + l16;
    short8 b0 = *(const short8*)(kb + (size_t)row * HD + lk*8);
    short8 b1 = *(const short8*)(kb + (size_t)row * HD + 32 + lk*8);
    sacc[nt] = __builtin_amdgcn_mfma_f32_16x16x32_bf16(a0, b0, sacc[nt], 0, 0, 0);
    sacc[nt] = __builtin_amdgcn_mfma_f32_16x16x32_bf16(a1, b1, sacc[nt], 0, 0, 0);
  }

  #pragma unroll
  for (int nt = 0; nt < 13; ++nt){
    int key = nt*16 + l16;
    int kh = key / 14, kw = key - 14*kh;
    bool kok = key < HW;
    #pragma unroll
    for (int i = 0; i < 4; ++i){
      int rl = lk*4 + i;
      float s = sacc[nt][i] * 0.125f + relg[rl*29 + kh] + relg[rl*29 + 14 + kw];
      sacc[nt][i] = kok ? s : -1e30f;
    }
  }

  #pragma unroll
  for (int i = 0; i < 4; ++i){
    float m = -1e30f;
    #pragma unroll
    for (int nt = 0; nt < 13; ++nt) m = fmaxf(m, sacc[nt][i]);
    #pragma unroll
    for (int d = 1; d < 16; d <<= 1) m = fmaxf(m, __shfl_xor(m, d, 64));
    float sum = 0.f;
    #pragma unroll
    for (int nt = 0; nt < 13; ++nt){
      float p = __expf(sacc[nt][i] - m);
      sacc[nt][i] = p; sum += p;
    }
    #pragma unroll
    for (int d = 1; d < 16; d <<= 1) sum += __shfl_xor(sum, d, 64);
    float inv = 1.f / sum;
    #pragma unroll
    for (int nt = 0; nt < 13; ++nt) sacc[nt][i] *= inv;
  }

  #pragma unroll
  for (int nt = 0; nt < 14; ++nt){
    #pragma unroll
    for (int i = 0; i < 4; ++i){
      int prow = lk*4 + i;
      int key = nt*16 + l16;
      float pv = (nt < 13) ? sacc[nt][i] : 0.f;
      if (key >= HW || mt*16 + prow >= HW) pv = 0.f;
      int c2 = key * 2;
      if (nt < 12) c2 ^= (prow & 7) << 4;
      *(u16*)(pbase + prow*448 + c2) = f2bf(pv);
    }
  }
  LGKM_FENCE();

  f32x4 oacc[4];
  #pragma unroll
  for (int n = 0; n < 4; ++n) oacc[n] = z;
  #pragma unroll
  for (int kt = 0; kt < 7; ++kt){
    int c2 = kt*64 + lk*16;
    if (kt < 6) c2 ^= (l16 & 7) << 4;
    short8 pa = *(const short8*)(pbase + l16*448 + c2);
    #pragma unroll
    for (int dt = 0; dt < 4; ++dt){
      short8 bv = *(const short8*)(vb + (size_t)(dt*16 + l16) * SPV + kt*32 + lk*8);
      oacc[dt] = __builtin_amdgcn_mfma_f32_16x16x32_bf16(bv, pa, oacc[dt], 0, 0, 0);
    }
  }
  int qrow = mt*16 + l16;
  if (qrow < HW){
    u16* orow = ao + ((size_t)bb * HW + qrow) * DIM + hh * HD;
    #pragma unroll
    for (int dt = 0; dt < 4; ++dt){
      u32 lo = cvtpk_bf16(oacc[dt][0], oacc[dt][1]);
      u32 hi = cvtpk_bf16(oacc[dt][2], oacc[dt][3]);
      u32* dst = (u32*)(orow + dt*16 + lk*4);
      dst[0] = lo; dst[1] = hi;
    }
  }
}

extern "C" void kernel_launch(void* const* d_in, const int* in_sizes, int n_in,
                              void* d_out, int out_size, void* d_ws, size_t ws_size,
                              hipStream_t stream)
{
  const float* x      = (const float*)d_in[0];
  const float* qkv_w  = (const float*)d_in[1];
  const float* qkv_b  = (const float*)d_in[2];
  const float* proj_w = (const float*)d_in[3];
  const float* proj_b = (const float*)d_in[4];
  const float* rph    = (const float*)d_in[5];
  const float* rpw    = (const float*)d_in[6];
  float* out = (float*)d_out;
  char* ws = (char*)d_ws;

  size_t off = 0;
  auto alloc = [&](size_t b){ size_t r = off; off += (b + 255) & ~(size_t)255; return r; };
  u16* wqkvT = (u16*)(ws + alloc((size_t)3072*1024*2));
  u16* wprojT= (u16*)(ws + alloc((size_t)1024*1024*2));
  u16* qg    = (u16*)(ws + alloc((size_t)NBH*SP*HD*2));
  u16* kg    = (u16*)(ws + alloc((size_t)NBH*SP*HD*2));
  u16* vTg   = (u16*)(ws + alloc((size_t)NBH*HD*SPV*2));
  u16* rphb  = (u16*)(ws + alloc((size_t)32*64*2));
  u16* rpwb  = (u16*)(ws + alloc((size_t)32*64*2));
  u16* xb    = (u16*)(ws + alloc((size_t)12544*1024*2));
  u16* ao    = xb;   // disjoint lifetimes

  hipFuncSetAttribute((const void*)k_g256<0,true>,  hipFuncAttributeMaxDynamicSharedMemorySize, 131072);
  hipFuncSetAttribute((const void*)k_g256<0,false>, hipFuncAttributeMaxDynamicSharedMemorySize, 131072);
  hipFuncSetAttribute((const void*)k_g256<1,true>,  hipFuncAttributeMaxDynamicSharedMemorySize, 131072);

  hipMemsetAsync(vTg, 0, (size_t)NBH*HD*SPV*2, stream);

  k_xcvt<<<(12544*1024/8 + 255)/256, 256, 0, stream>>>(x, xb, 12544*1024/8);
  k_wT<<<dim3(96, 32), 256, 0, stream>>>(qkv_w, wqkvT, 1024, 3072);
  k_wT<<<dim3(32, 32), 256, 0, stream>>>(proj_w, wprojT, 1024, 1024);
  k_rprep<<<1, 256, 0, stream>>>(rph, rpw, rphb, rpwb);

  // QKV: q/k columns (0..2047, swapped epilogue) and v columns (2048.., vT scatter)
  k_g256<0,true><<<49*8, 512, 131072, stream>>>(xb, wqkvT, qkv_b, qg, kg, nullptr, nullptr,
                                                1024, 3072, 49, 8, 0);
  k_g256<0,false><<<49*4, 512, 131072, stream>>>(xb, wqkvT, qkv_b, nullptr, nullptr, vTg, nullptr,
                                                 1024, 3072, 49, 4, 8);
  k_attn<<<3328, 256, 0, stream>>>(qg, kg, vTg, rphb, rpwb, ao);
  k_g256<1,true><<<49*4, 512, 131072, stream>>>(ao, wprojT, proj_b, nullptr, nullptr, nullptr, out,
                                                1024, 1024, 49, 4, 0);
}

// Round 7
// 257.056 us; speedup vs baseline: 1.9960x; 1.0123x over previous
//
#include <hip/hip_runtime.h>
#include <cstdint>
#include <cstddef>

typedef unsigned short u16;
typedef unsigned int u32;
typedef float f32x4 __attribute__((ext_vector_type(4)));
typedef short short8 __attribute__((ext_vector_type(8)));
typedef u32 u32x2 __attribute__((ext_vector_type(2)));

#define HW 196
#define DIM 1024
#define HD 64
#define SP 208
#define SPV 224
#define NBH 1024

__device__ __forceinline__ float bf2f(u16 x){
  union { u32 u; float f; } c; c.u = ((u32)x) << 16; return c.f;
}
__device__ __forceinline__ u16 f2bf(float f){
  union { float f; u32 u; } c; c.f = f;
  return (u16)((c.u + 0x7fffu + ((c.u >> 16) & 1u)) >> 16);
}
__device__ __forceinline__ u32 cvtpk_bf16(float lo, float hi){
  u32 r;
  asm("v_cvt_pk_bf16_f32 %0, %1, %2" : "=v"(r) : "v"(lo), "v"(hi));
  return r;
}
#define LGKM_FENCE() do { \
    asm volatile("s_waitcnt lgkmcnt(0)" ::: "memory"); \
    __builtin_amdgcn_sched_barrier(0); \
  } while (0)
// DS-order fence that still lets VMEM/VALU cross (mask = all but DS*)
#define DS_FENCE() do { \
    asm volatile("s_waitcnt lgkmcnt(0)" ::: "memory"); \
    __builtin_amdgcn_sched_barrier(0x7F); \
  } while (0)
#define WAITV4() asm volatile("s_waitcnt vmcnt(4)" ::: "memory")
#define BAR() __builtin_amdgcn_s_barrier()

typedef __attribute__((address_space(3))) void lds_void_t;
typedef __attribute__((address_space(1))) const void glb_void_t;
__device__ __forceinline__ void gload_lds16(const void* g, void* l){
  __builtin_amdgcn_global_load_lds((glb_void_t*)g, (lds_void_t*)l, 16, 0, 0);
}

// ---- x f32 -> bf16 convert ----
__global__ __launch_bounds__(256) void k_xcvt(const float* __restrict__ x,
                                              u16* __restrict__ xb, int n8){
  int i = blockIdx.x * 256 + threadIdx.x;
  if (i < n8){
    const f32x4* p = (const f32x4*)(x + (size_t)i * 8);
    f32x4 v0 = p[0], v1 = p[1];
    short8 t;
    #pragma unroll
    for (int e = 0; e < 4; ++e){
      t[e]   = (short)f2bf(v0[e]);
      t[4+e] = (short)f2bf(v1[e]);
    }
    *(short8*)(xb + (size_t)i * 8) = t;
  }
}

// ---- rel-pos tables f32[27][64] -> bf16[32][64], pad rows zero ----
__global__ __launch_bounds__(256) void k_rprep(const float* __restrict__ rph,
                                               const float* __restrict__ rpw,
                                               u16* __restrict__ rphb,
                                               u16* __restrict__ rpwb){
  int r = threadIdx.x >> 3, cc = (threadIdx.x & 7) * 8;
  #pragma unroll
  for (int t = 0; t < 2; ++t){
    const float* src = t ? rpw : rph;
    u16* dst = t ? rpwb : rphb;
    short8 v;
    #pragma unroll
    for (int e = 0; e < 8; ++e)
      v[e] = (r < 27) ? (short)f2bf(src[(size_t)r * 64 + cc + e]) : (short)0;
    *(short8*)(dst + (size_t)r * 64 + cc) = v;
  }
}

// ---- weight transpose + convert: w[K][N] f32 -> wT[N][K] bf16 ----
__global__ __launch_bounds__(256) void k_wT(const float* __restrict__ w,
                                            u16* __restrict__ wT, int K, int N){
  __shared__ float t[32][33];
  int n0 = blockIdx.x * 32, k0 = blockIdx.y * 32;
  int c = threadIdx.x & 31, rr = threadIdx.x >> 5;
  #pragma unroll
  for (int i = 0; i < 4; ++i){
    int r = rr + i*8;
    t[r][c] = w[(size_t)(k0 + r) * N + n0 + c];
  }
  __syncthreads();
  #pragma unroll
  for (int i = 0; i < 4; ++i){
    int r = rr + i*8;
    wT[(size_t)(n0 + r) * K + k0 + c] = f2bf(t[c][r]);
  }
}

// ================= 256x256 8-phase GEMM (T2+T3+T4+T5) =================
// Identical schedule to R6 (verified). SW epilogue now scales the k-third by
// 0.125 (exact bf16 exponent shift) so attention folds qk-scale for free.
template<int MODE, bool SW>
__global__ __launch_bounds__(512, 2) void k_g256(const u16* __restrict__ Ab,
    const u16* __restrict__ Bt, const float* __restrict__ bias,
    u16* __restrict__ qg, u16* __restrict__ kg, u16* __restrict__ vTg,
    float* __restrict__ outf, int K, int N, int ntm, int ntn, int cyoff)
{
  extern __shared__ __align__(16) u16 smem[];   // [d][ab][ks][256][32] = 128 KiB
  const int tid = threadIdx.x;
  const int lane = tid & 63, wv = tid >> 6;
  const int wr = wv >> 2, wc = wv & 3;
  const int l16 = lane & 15, lk = lane >> 4;

  const int nwg = ntm * ntn;
  int bid = blockIdx.x;
  int q8 = nwg >> 3, r8 = nwg & 7;
  int xcd = bid & 7, loc = bid >> 3;
  int wgid = (xcd < r8 ? xcd*(q8+1) : r8*(q8+1) + (xcd - r8)*q8) + loc;
  int gsz = 8 * ntn;
  int g = wgid / gsz, rem = wgid - g * gsz;
  int gm = ntm - g * 8; if (gm > 8) gm = 8;
  int ry = g * 8 + rem % gm;
  int cy = rem / gm;
  const size_t m0 = (size_t)ry * 256;
  const size_t n0 = (size_t)(cyoff + cy) * 256;
  const int nk = K >> 6;

  auto off = [&](int d, int ab, int ks){ return ((d*2 + ab)*2 + ks) * 8192; };

  auto stageH = [&](int d, int ab, int ks, int tile){
    const u16* src = ab ? Bt : Ab;
    size_t rb = ab ? n0 : m0;
    int c = (lane & 3) ^ ((lane >> 3) & 3);
    #pragma unroll
    for (int i = 0; i < 2; ++i){
      int rh = 32*wv + 16*i + (lane >> 2);
      gload_lds16(src + (rb + rh) * (size_t)K + tile*64 + ks*32 + c*8,
                  smem + off(d, ab, ks) + (32*wv + 16*i) * 32);
    }
  };
  auto ldA = [&](short8* a, int d, int ks, int h){
    #pragma unroll
    for (int m2 = 0; m2 < 4; ++m2){
      int r = wr*128 + h*64 + m2*16 + l16;
      a[m2] = *(const short8*)(smem + off(d,0,ks) + r*32 + ((lk ^ ((r>>1)&3)) << 3));
    }
  };
  auto ldB = [&](short8* b, int d, int ks){
    #pragma unroll
    for (int ni = 0; ni < 4; ++ni){
      int r = wc*64 + ni*16 + l16;
      b[ni] = *(const short8*)(smem + off(d,1,ks) + r*32 + ((lk ^ ((r>>1)&3)) << 3));
    }
  };

  f32x4 acc[8][4] = {};
  auto mm = [&](int h, short8* a, short8* b){
    __builtin_amdgcn_s_setprio(1);
    #pragma unroll
    for (int m2 = 0; m2 < 4; ++m2)
      #pragma unroll
      for (int ni = 0; ni < 4; ++ni){
        if constexpr (SW)
          acc[h*4+m2][ni] = __builtin_amdgcn_mfma_f32_16x16x32_bf16(b[ni], a[m2], acc[h*4+m2][ni], 0, 0, 0);
        else
          acc[h*4+m2][ni] = __builtin_amdgcn_mfma_f32_16x16x32_bf16(a[m2], b[ni], acc[h*4+m2][ni], 0, 0, 0);
      }
    __builtin_amdgcn_s_setprio(0);
  };

  stageH(0, 0, 0, 0); stageH(0, 1, 0, 0); stageH(0, 0, 1, 0); stageH(0, 1, 1, 0);
  WAITV4(); BAR();

  #pragma unroll 1
  for (int kt = 0; kt < nk; ++kt){
    const int d = kt & 1, dn = d ^ 1;
    const int tn = (kt + 1 < nk) ? kt + 1 : nk - 1;
    short8 a[4], b0[4], b1[4];
    ldA(a, d, 0, 0); ldB(b0, d, 0);
    stageH(dn, 0, 0, tn);
    BAR(); LGKM_FENCE();
    mm(0, a, b0);
    BAR();
    ldA(a, d, 0, 1);
    stageH(dn, 1, 0, tn);
    WAITV4();
    BAR(); LGKM_FENCE();
    mm(1, a, b0);
    BAR();
    ldA(a, d, 1, 0); ldB(b1, d, 1);
    stageH(dn, 0, 1, tn);
    BAR(); LGKM_FENCE();
    mm(0, a, b1);
    BAR();
    ldA(a, d, 1, 1);
    stageH(dn, 1, 1, tn);
    WAITV4();
    BAR(); LGKM_FENCE();
    mm(1, a, b1);
    BAR();
  }

  const int rowb = (int)m0 + wr*128;
  const int colb = (int)n0 + wc*64;
  if constexpr (MODE == 1){
    #pragma unroll
    for (int mi = 0; mi < 8; ++mi){
      int r = rowb + mi*16 + l16;
      float* orow = outf + (size_t)r * N;
      #pragma unroll
      for (int ni = 0; ni < 4; ++ni){
        int c0 = colb + ni*16 + lk*4;
        f32x4 bz = *(const f32x4*)(bias + c0);
        f32x4 v = acc[mi][ni] + bz;
        *(f32x4*)(orow + c0) = v;
      }
    }
  } else if constexpr (SW){
    // q/k thirds: row-major [bh][n][cc]; k-third scaled by 0.125 (qk-scale fold)
    const int t3 = colb >> 10;
    u16* dst0 = (t3 == 0) ? qg : kg;
    const float sc = (t3 == 0) ? 1.0f : 0.125f;
    #pragma unroll
    for (int mi = 0; mi < 8; ++mi){
      int r = rowb + mi*16 + l16;
      int b = r / 196, n = r - b * 196;
      #pragma unroll
      for (int ni = 0; ni < 4; ++ni){
        int rr2 = ((colb & 1023) + ni*16);
        int hh = rr2 >> 6, ccb = (rr2 & 63) + lk*4;
        const float* bz = bias + colb + ni*16 + lk*4;
        u32 w0 = cvtpk_bf16((acc[mi][ni][0] + bz[0])*sc, (acc[mi][ni][1] + bz[1])*sc);
        u32 w1 = cvtpk_bf16((acc[mi][ni][2] + bz[2])*sc, (acc[mi][ni][3] + bz[3])*sc);
        u32* dst = (u32*)(dst0 + ((size_t)(hh*64 + b) * SP + n) * HD + ccb);
        dst[0] = w0; dst[1] = w1;
      }
    }
  } else {
    #pragma unroll
    for (int mi = 0; mi < 8; ++mi){
      int r4 = rowb + mi*16 + lk*4;
      int b = r4 / 196, n4 = r4 - b * 196;
      #pragma unroll
      for (int ni = 0; ni < 4; ++ni){
        int rr2 = ((colb & 1023) + ni*16);
        int hh = rr2 >> 6, cc = (rr2 & 63) + l16;
        float bz = bias[colb + ni*16 + l16];
        u32 w0 = cvtpk_bf16(acc[mi][ni][0] + bz, acc[mi][ni][1] + bz);
        u32 w1 = cvtpk_bf16(acc[mi][ni][2] + bz, acc[mi][ni][3] + bz);
        u32* dst = (u32*)(vTg + ((size_t)(hh*64 + b) * HD + cc) * SPV + n4);
        dst[0] = w0; dst[1] = w1;
      }
    }
  }
}

// ---- fused attention: one WAVE per (bh, q-tile); swapped QK^T (lane-local q) ----
// per-wave LDS 7424B: relT[16][68] f32 (4352B) aliased by Pp[16][116] u32.
// S held as S[k=nt*16+lk*4+i][q=l16]; softmax lane-local + 2 shfl_xor;
// P packed via cvt_pk -> 13 ds_write_b64; PV reads ds_read_b128.
__global__ __launch_bounds__(256) void k_attn(
    const u16* __restrict__ qg, const u16* __restrict__ kg, const u16* __restrict__ vTg,
    const u16* __restrict__ rphb, const u16* __restrict__ rpwb,
    u16* __restrict__ ao)
{
  __shared__ __align__(16) char smem[4 * 7424];
  const int tid = threadIdx.x, lane = tid & 63, wvi = tid >> 6;
  const int l16 = lane & 15, lk = lane >> 4;
  char*  wbase = smem + wvi * 7424;
  float* relT  = (float*)wbase;            // [16][68] f32
  u32*   Pp    = (u32*)wbase;              // [16][116] u32 (aliases relT; disjoint lifetime)

  int b = blockIdx.x;
  int sb = (b & 7) * 416 + (b >> 3);
  int j  = sb * 4 + wvi;
  int bh = j / 13;
  int mt = j - bh * 13;
  const int hh = bh >> 6, bb = bh & 63;
  const u16* qb = qg  + (size_t)bh * SP * HD;
  const u16* kb = kg  + (size_t)bh * SP * HD;
  const u16* vb = vTg + (size_t)bh * HD * SPV;

  const short8 a0 = *(const short8*)(qb + (size_t)(mt*16 + l16) * HD + lk*8);
  const short8 a1 = *(const short8*)(qb + (size_t)(mt*16 + l16) * HD + 32 + lk*8);

  // rel tables via MFMA: lane(l16,lk) reg i = T[delta=dt*16+lk*4+i][q=l16]
  {
    f32x4 z = {0.f,0.f,0.f,0.f};
    f32x4 racc[2][2] = {{z,z},{z,z}};
    #pragma unroll
    for (int dt = 0; dt < 2; ++dt){
      short8 h0 = *(const short8*)(rphb + (size_t)(dt*16 + l16) * 64 + lk*8);
      short8 h1 = *(const short8*)(rphb + (size_t)(dt*16 + l16) * 64 + 32 + lk*8);
      short8 w0 = *(const short8*)(rpwb + (size_t)(dt*16 + l16) * 64 + lk*8);
      short8 w1 = *(const short8*)(rpwb + (size_t)(dt*16 + l16) * 64 + 32 + lk*8);
      racc[0][dt] = __builtin_amdgcn_mfma_f32_16x16x32_bf16(h0, a0, racc[0][dt], 0, 0, 0);
      racc[0][dt] = __builtin_amdgcn_mfma_f32_16x16x32_bf16(h1, a1, racc[0][dt], 0, 0, 0);
      racc[1][dt] = __builtin_amdgcn_mfma_f32_16x16x32_bf16(w0, a0, racc[1][dt], 0, 0, 0);
      racc[1][dt] = __builtin_amdgcn_mfma_f32_16x16x32_bf16(w1, a1, racc[1][dt], 0, 0, 0);
    }
    // relT[q=l16][t*32 + delta] — 16B-aligned f32x4 stores (row stride 272B)
    #pragma unroll
    for (int t = 0; t < 2; ++t)
      #pragma unroll
      for (int dt = 0; dt < 2; ++dt)
        *(f32x4*)(relT + l16*68 + t*32 + dt*16 + lk*4) = racc[t][dt];
  }
  DS_FENCE();

  // bias as MFMA C-in: sacc[nt][i] = Th[q][qh+13-kh] + Tw[q][qw+13-kw]
  int qr = mt*16 + l16;
  int qrc = qr > HW-1 ? HW-1 : qr;
  int qh = qrc / 14, qw = qrc - 14*qh;
  const float* rrow = relT + l16*68;
  const int dh0 = qh + 13, dw0 = 32 + qw + 13;
  const int lk4 = lk*4;

  f32x4 sacc[13];
  #pragma unroll
  for (int nt = 0; nt < 13; ++nt){
    #pragma unroll
    for (int i = 0; i < 4; ++i){
      int k = nt*16 + lk4 + i;
      int kh = (k * 4682) >> 16;               // k/14 for k<224
      if (nt == 12 && kh > 13) kh = 13;        // clamp pad-key index (masked below)
      int kw = k - kh*14;
      float bias = rrow[dh0 - kh] + rrow[dw0 - kw];
      sacc[nt][i] = (nt == 12 && lk != 0) ? -1e30f : bias;  // pad keys k>=196
    }
  }

  // QK^T swapped: sacc[nt] += Ks . Q  (K pre-scaled by 0.125 at source)
  #pragma unroll
  for (int nt = 0; nt < 13; ++nt){
    int row = nt*16 + l16;
    short8 b0 = *(const short8*)(kb + (size_t)row * HD + lk*8);
    short8 b1 = *(const short8*)(kb + (size_t)row * HD + 32 + lk*8);
    sacc[nt] = __builtin_amdgcn_mfma_f32_16x16x32_bf16(b0, a0, sacc[nt], 0, 0, 0);
    sacc[nt] = __builtin_amdgcn_mfma_f32_16x16x32_bf16(b1, a1, sacc[nt], 0, 0, 0);
  }

  // softmax for q=l16: in-register tree over 52 + 2 shfl_xor across lk
  float m;
  {
    float t0[13];
    #pragma unroll
    for (int nt = 0; nt < 13; ++nt)
      t0[nt] = fmaxf(fmaxf(sacc[nt][0], sacc[nt][1]), fmaxf(sacc[nt][2], sacc[nt][3]));
    float a01 = fmaxf(t0[0], t0[1]),  a23 = fmaxf(t0[2], t0[3]);
    float a45 = fmaxf(t0[4], t0[5]),  a67 = fmaxf(t0[6], t0[7]);
    float a89 = fmaxf(t0[8], t0[9]),  aab = fmaxf(t0[10], t0[11]);
    m = fmaxf(fmaxf(fmaxf(a01, a23), fmaxf(a45, a67)), fmaxf(fmaxf(a89, aab), t0[12]));
  }
  m = fmaxf(m, __shfl_xor(m, 16, 64));
  m = fmaxf(m, __shfl_xor(m, 32, 64));
  float sum;
  {
    float s4[13];
    #pragma unroll
    for (int nt = 0; nt < 13; ++nt){
      #pragma unroll
      for (int i = 0; i < 4; ++i)
        sacc[nt][i] = __expf(sacc[nt][i] - m);   // pad keys -> exp(-huge) = 0
      s4[nt] = (sacc[nt][0] + sacc[nt][1]) + (sacc[nt][2] + sacc[nt][3]);
    }
    float b01 = s4[0]+s4[1], b23 = s4[2]+s4[3], b45 = s4[4]+s4[5];
    float b67 = s4[6]+s4[7], b89 = s4[8]+s4[9], bab = s4[10]+s4[11];
    sum = ((b01+b23) + (b45+b67)) + ((b89+bab) + s4[12]);
  }
  sum += __shfl_xor(sum, 16, 64);
  sum += __shfl_xor(sum, 32, 64);
  float inv = 1.0f / sum;                        // folded into output (P left unnormalized)

  // pack P -> Pp[q=l16][k/2] as bf16 pairs (aliases relT: DS-order fence first)
  DS_FENCE();
  u32* prow = Pp + l16*116;
  #pragma unroll
  for (int nt = 0; nt < 13; ++nt){
    u32x2 wpk;
    wpk[0] = cvtpk_bf16(sacc[nt][0], sacc[nt][1]);
    wpk[1] = cvtpk_bf16(sacc[nt][2], sacc[nt][3]);
    *(u32x2*)(prow + nt*8 + lk*2) = wpk;         // u32 idx = k>>1 (consecutive)
  }
  { u32x2 zz = {0u, 0u}; *(u32x2*)(prow + 104 + lk*2) = zz; }  // k = 208..223 -> 0
  DS_FENCE();

  // PV: pa = ds_read_b128 of Pp row; V^T B-frags from global
  f32x4 z = {0.f,0.f,0.f,0.f};
  f32x4 oacc[4] = {z,z,z,z};
  #pragma unroll
  for (int kt = 0; kt < 7; ++kt){
    short8 pa = *(const short8*)(prow + kt*16 + lk4);
    #pragma unroll
    for (int dt = 0; dt < 4; ++dt){
      short8 bv = *(const short8*)(vb + (size_t)(dt*16 + l16) * SPV + kt*32 + lk*8);
      oacc[dt] = __builtin_amdgcn_mfma_f32_16x16x32_bf16(bv, pa, oacc[dt], 0, 0, 0);
    }
  }
  // O[d=dt*16+lk*4+i][q=l16]; normalize by inv (per-lane q) at the store
  int qrow = mt*16 + l16;
  if (qrow < HW){
    u16* orow = ao + ((size_t)bb * HW + qrow) * DIM + hh * HD;
    #pragma unroll
    for (int dt = 0; dt < 4; ++dt){
      u32 lo = cvtpk_bf16(oacc[dt][0]*inv, oacc[dt][1]*inv);
      u32 hi = cvtpk_bf16(oacc[dt][2]*inv, oacc[dt][3]*inv);
      u32* dst = (u32*)(orow + dt*16 + lk4);
      dst[0] = lo; dst[1] = hi;
    }
  }
}

extern "C" void kernel_launch(void* const* d_in, const int* in_sizes, int n_in,
                              void* d_out, int out_size, void* d_ws, size_t ws_size,
                              hipStream_t stream)
{
  const float* x      = (const float*)d_in[0];
  const float* qkv_w  = (const float*)d_in[1];
  const float* qkv_b  = (const float*)d_in[2];
  const float* proj_w = (const float*)d_in[3];
  const float* proj_b = (const float*)d_in[4];
  const float* rph    = (const float*)d_in[5];
  const float* rpw    = (const float*)d_in[6];
  float* out = (float*)d_out;
  char* ws = (char*)d_ws;

  size_t off = 0;
  auto alloc = [&](size_t b){ size_t r = off; off += (b + 255) & ~(size_t)255; return r; };
  u16* wqkvT = (u16*)(ws + alloc((size_t)3072*1024*2));
  u16* wprojT= (u16*)(ws + alloc((size_t)1024*1024*2));
  u16* qg    = (u16*)(ws + alloc((size_t)NBH*SP*HD*2));
  u16* kg    = (u16*)(ws + alloc((size_t)NBH*SP*HD*2));
  u16* vTg   = (u16*)(ws + alloc((size_t)NBH*HD*SPV*2));
  u16* rphb  = (u16*)(ws + alloc((size_t)32*64*2));
  u16* rpwb  = (u16*)(ws + alloc((size_t)32*64*2));
  u16* xb    = (u16*)(ws + alloc((size_t)12544*1024*2));
  u16* ao    = xb;   // disjoint lifetimes

  hipFuncSetAttribute((const void*)k_g256<0,true>,  hipFuncAttributeMaxDynamicSharedMemorySize, 131072);
  hipFuncSetAttribute((const void*)k_g256<0,false>, hipFuncAttributeMaxDynamicSharedMemorySize, 131072);
  hipFuncSetAttribute((const void*)k_g256<1,true>,  hipFuncAttributeMaxDynamicSharedMemorySize, 131072);

  hipMemsetAsync(vTg, 0, (size_t)NBH*HD*SPV*2, stream);

  k_xcvt<<<(12544*1024/8 + 255)/256, 256, 0, stream>>>(x, xb, 12544*1024/8);
  k_wT<<<dim3(96, 32), 256, 0, stream>>>(qkv_w, wqkvT, 1024, 3072);
  k_wT<<<dim3(32, 32), 256, 0, stream>>>(proj_w, wprojT, 1024, 1024);
  k_rprep<<<1, 256, 0, stream>>>(rph, rpw, rphb, rpwb);

  k_g256<0,true><<<49*8, 512, 131072, stream>>>(xb, wqkvT, qkv_b, qg, kg, nullptr, nullptr,
                                                1024, 3072, 49, 8, 0);
  k_g256<0,false><<<49*4, 512, 131072, stream>>>(xb, wqkvT, qkv_b, nullptr, nullptr, vTg, nullptr,
                                                 1024, 3072, 49, 4, 8);
  k_attn<<<3328, 256, 0, stream>>>(qg, kg, vTg, rphb, rpwb, ao);
  k_g256<1,true><<<49*4, 512, 131072, stream>>>(ao, wprojT, proj_b, nullptr, nullptr, nullptr, out,
                                                1024, 1024, 49, 4, 0);
}

// Round 8
// 227.955 us; speedup vs baseline: 2.2508x; 1.1277x over previous
//
#include <hip/hip_runtime.h>
#include <cstdint>
#include <cstddef>

typedef unsigned short u16;
typedef unsigned int u32;
typedef float f32x4 __attribute__((ext_vector_type(4)));
typedef short short8 __attribute__((ext_vector_type(8)));
typedef u32 u32x2 __attribute__((ext_vector_type(2)));

#define HW 196
#define DIM 1024
#define HD 64
#define SP 208
#define SPV 224
#define NBH 1024

__device__ __forceinline__ float bf2f(u16 x){
  union { u32 u; float f; } c; c.u = ((u32)x) << 16; return c.f;
}
__device__ __forceinline__ u16 f2bf(float f){
  union { float f; u32 u; } c; c.f = f;
  return (u16)((c.u + 0x7fffu + ((c.u >> 16) & 1u)) >> 16);
}
__device__ __forceinline__ u32 cvtpk_bf16(float lo, float hi){
  u32 r;
  asm("v_cvt_pk_bf16_f32 %0, %1, %2" : "=v"(r) : "v"(lo), "v"(hi));
  return r;
}
#define LGKM_FENCE() do { \
    asm volatile("s_waitcnt lgkmcnt(0)" ::: "memory"); \
    __builtin_amdgcn_sched_barrier(0); \
  } while (0)
// DS-order fence that still lets VMEM/VALU cross (mask = all but DS*)
#define DS_FENCE() do { \
    asm volatile("s_waitcnt lgkmcnt(0)" ::: "memory"); \
    __builtin_amdgcn_sched_barrier(0x7F); \
  } while (0)
#define WAITV4() asm volatile("s_waitcnt vmcnt(4)" ::: "memory")
#define BAR() __builtin_amdgcn_s_barrier()

typedef __attribute__((address_space(3))) void lds_void_t;
typedef __attribute__((address_space(1))) const void glb_void_t;
__device__ __forceinline__ void gload_lds16(const void* g, void* l){
  __builtin_amdgcn_global_load_lds((glb_void_t*)g, (lds_void_t*)l, 16, 0, 0);
}

// ---- x f32 -> bf16 convert ----
__global__ __launch_bounds__(256) void k_xcvt(const float* __restrict__ x,
                                              u16* __restrict__ xb, int n8){
  int i = blockIdx.x * 256 + threadIdx.x;
  if (i < n8){
    const f32x4* p = (const f32x4*)(x + (size_t)i * 8);
    f32x4 v0 = p[0], v1 = p[1];
    short8 t;
    #pragma unroll
    for (int e = 0; e < 4; ++e){
      t[e]   = (short)f2bf(v0[e]);
      t[4+e] = (short)f2bf(v1[e]);
    }
    *(short8*)(xb + (size_t)i * 8) = t;
  }
}

// ---- rel-pos tables f32[27][64] -> bf16[32][64], pad rows zero ----
__global__ __launch_bounds__(256) void k_rprep(const float* __restrict__ rph,
                                               const float* __restrict__ rpw,
                                               u16* __restrict__ rphb,
                                               u16* __restrict__ rpwb){
  int r = threadIdx.x >> 3, cc = (threadIdx.x & 7) * 8;
  #pragma unroll
  for (int t = 0; t < 2; ++t){
    const float* src = t ? rpw : rph;
    u16* dst = t ? rpwb : rphb;
    short8 v;
    #pragma unroll
    for (int e = 0; e < 8; ++e)
      v[e] = (r < 27) ? (short)f2bf(src[(size_t)r * 64 + cc + e]) : (short)0;
    *(short8*)(dst + (size_t)r * 64 + cc) = v;
  }
}

// ---- weight transpose + convert: w[K][N] f32 -> wT[N][K] bf16 ----
__global__ __launch_bounds__(256) void k_wT(const float* __restrict__ w,
                                            u16* __restrict__ wT, int K, int N){
  __shared__ float t[32][33];
  int n0 = blockIdx.x * 32, k0 = blockIdx.y * 32;
  int c = threadIdx.x & 31, rr = threadIdx.x >> 5;
  #pragma unroll
  for (int i = 0; i < 4; ++i){
    int r = rr + i*8;
    t[r][c] = w[(size_t)(k0 + r) * N + n0 + c];
  }
  __syncthreads();
  #pragma unroll
  for (int i = 0; i < 4; ++i){
    int r = rr + i*8;
    wT[(size_t)(n0 + r) * K + k0 + c] = f2bf(t[c][r]);
  }
}

// ================= 256x256 8-phase GEMM (T2+T3+T4+T5) =================
// Schedule identical to the R6/R7-verified kernel. MFMA always operand-swapped
// (C^T fragments). MODE 0: merged QKV epilogue, runtime branch per column
// third (thirds are 1024-aligned; a 64-col wave tile never straddles):
//   t3<2 : q/k row-major scatter, 8B stores; k scaled by 0.125 (qk-scale fold)
//   t3==2: vT scatter, 4 scalar u16 stores per frag (1/3 of blocks)
// MODE 1: f32 out + bias, f32x4 stores.
template<int MODE>
__global__ __launch_bounds__(512, 2) void k_g256(const u16* __restrict__ Ab,
    const u16* __restrict__ Bt, const float* __restrict__ bias,
    u16* __restrict__ qg, u16* __restrict__ kg, u16* __restrict__ vTg,
    float* __restrict__ outf, int K, int N, int ntm, int ntn)
{
  extern __shared__ __align__(16) u16 smem[];   // [d][ab][ks][256][32] = 128 KiB
  const int tid = threadIdx.x;
  const int lane = tid & 63, wv = tid >> 6;
  const int wr = wv >> 2, wc = wv & 3;
  const int l16 = lane & 15, lk = lane >> 4;

  const int nwg = ntm * ntn;
  int bid = blockIdx.x;
  int q8 = nwg >> 3, r8 = nwg & 7;
  int xcd = bid & 7, loc = bid >> 3;
  int wgid = (xcd < r8 ? xcd*(q8+1) : r8*(q8+1) + (xcd - r8)*q8) + loc;
  int gsz = 8 * ntn;
  int g = wgid / gsz, rem = wgid - g * gsz;
  int gm = ntm - g * 8; if (gm > 8) gm = 8;
  int ry = g * 8 + rem % gm;
  int cy = rem / gm;
  const size_t m0 = (size_t)ry * 256;
  const size_t n0 = (size_t)cy * 256;
  const int nk = K >> 6;

  auto off = [&](int d, int ab, int ks){ return ((d*2 + ab)*2 + ks) * 8192; };

  auto stageH = [&](int d, int ab, int ks, int tile){
    const u16* src = ab ? Bt : Ab;
    size_t rb = ab ? n0 : m0;
    int c = (lane & 3) ^ ((lane >> 3) & 3);
    #pragma unroll
    for (int i = 0; i < 2; ++i){
      int rh = 32*wv + 16*i + (lane >> 2);
      gload_lds16(src + (rb + rh) * (size_t)K + tile*64 + ks*32 + c*8,
                  smem + off(d, ab, ks) + (32*wv + 16*i) * 32);
    }
  };
  auto ldA = [&](short8* a, int d, int ks, int h){
    #pragma unroll
    for (int m2 = 0; m2 < 4; ++m2){
      int r = wr*128 + h*64 + m2*16 + l16;
      a[m2] = *(const short8*)(smem + off(d,0,ks) + r*32 + ((lk ^ ((r>>1)&3)) << 3));
    }
  };
  auto ldB = [&](short8* b, int d, int ks){
    #pragma unroll
    for (int ni = 0; ni < 4; ++ni){
      int r = wc*64 + ni*16 + l16;
      b[ni] = *(const short8*)(smem + off(d,1,ks) + r*32 + ((lk ^ ((r>>1)&3)) << 3));
    }
  };

  f32x4 acc[8][4] = {};
  auto mm = [&](int h, short8* a, short8* b){
    __builtin_amdgcn_s_setprio(1);
    #pragma unroll
    for (int m2 = 0; m2 < 4; ++m2)
      #pragma unroll
      for (int ni = 0; ni < 4; ++ni)
        acc[h*4+m2][ni] = __builtin_amdgcn_mfma_f32_16x16x32_bf16(b[ni], a[m2], acc[h*4+m2][ni], 0, 0, 0);
    __builtin_amdgcn_s_setprio(0);
  };

  stageH(0, 0, 0, 0); stageH(0, 1, 0, 0); stageH(0, 0, 1, 0); stageH(0, 1, 1, 0);
  WAITV4(); BAR();

  #pragma unroll 1
  for (int kt = 0; kt < nk; ++kt){
    const int d = kt & 1, dn = d ^ 1;
    const int tn = (kt + 1 < nk) ? kt + 1 : nk - 1;
    short8 a[4], b0[4], b1[4];
    ldA(a, d, 0, 0); ldB(b0, d, 0);
    stageH(dn, 0, 0, tn);
    BAR(); LGKM_FENCE();
    mm(0, a, b0);
    BAR();
    ldA(a, d, 0, 1);
    stageH(dn, 1, 0, tn);
    WAITV4();
    BAR(); LGKM_FENCE();
    mm(1, a, b0);
    BAR();
    ldA(a, d, 1, 0); ldB(b1, d, 1);
    stageH(dn, 0, 1, tn);
    BAR(); LGKM_FENCE();
    mm(0, a, b1);
    BAR();
    ldA(a, d, 1, 1);
    stageH(dn, 1, 1, tn);
    WAITV4();
    BAR(); LGKM_FENCE();
    mm(1, a, b1);
    BAR();
  }

  const int rowb = (int)m0 + wr*128;
  const int colb = (int)n0 + wc*64;
  if constexpr (MODE == 1){
    #pragma unroll
    for (int mi = 0; mi < 8; ++mi){
      int r = rowb + mi*16 + l16;
      float* orow = outf + (size_t)r * N;
      #pragma unroll
      for (int ni = 0; ni < 4; ++ni){
        int c0 = colb + ni*16 + lk*4;
        f32x4 bz = *(const f32x4*)(bias + c0);
        f32x4 v = acc[mi][ni] + bz;
        *(f32x4*)(orow + c0) = v;
      }
    }
  } else {
    const int t3 = colb >> 10;
    if (t3 < 2){
      u16* dst0 = (t3 == 0) ? qg : kg;
      const float sc = (t3 == 0) ? 1.0f : 0.125f;
      #pragma unroll
      for (int mi = 0; mi < 8; ++mi){
        int r = rowb + mi*16 + l16;
        int b = r / 196, n = r - b * 196;
        #pragma unroll
        for (int ni = 0; ni < 4; ++ni){
          int rr2 = ((colb & 1023) + ni*16);
          int hh = rr2 >> 6, ccb = (rr2 & 63) + lk*4;
          const float* bz = bias + colb + ni*16 + lk*4;
          u32 w0 = cvtpk_bf16((acc[mi][ni][0] + bz[0])*sc, (acc[mi][ni][1] + bz[1])*sc);
          u32 w1 = cvtpk_bf16((acc[mi][ni][2] + bz[2])*sc, (acc[mi][ni][3] + bz[3])*sc);
          u32* dst = (u32*)(dst0 + ((size_t)(hh*64 + b) * SP + n) * HD + ccb);
          dst[0] = w0; dst[1] = w1;
        }
      }
    } else {
      // v third (SW layout): per frag 4 scalar u16 stores, stride SPV elems
      #pragma unroll
      for (int mi = 0; mi < 8; ++mi){
        int r = rowb + mi*16 + l16;
        int b = r / 196, n = r - b * 196;
        #pragma unroll
        for (int ni = 0; ni < 4; ++ni){
          int col0 = colb + ni*16 + lk*4;
          f32x4 bz = *(const f32x4*)(bias + col0);
          int rem2 = col0 & 1023;
          int hh = rem2 >> 6, cc0 = rem2 & 63;
          u16* base = vTg + ((size_t)(hh*64 + b) * HD + cc0) * SPV + n;
          #pragma unroll
          for (int i = 0; i < 4; ++i)
            base[(size_t)i * SPV] = f2bf(acc[mi][ni][i] + bz[i]);
        }
      }
    }
  }
}

// ---- fused attention: one BLOCK per bh (13 waves); K/V staged once in LDS ----
// LDS: K[208 rows @144B] 29952 + V^T[64 rows @464B] 29696 + 13x per-wave
// P/relT 7424 = 156160 B. Padded strides give 2-way bank aliasing (free).
// Per wave (q-tile mt=wvi): R7-verified pipeline — rel via MFMA, bias as
// MFMA C-in, swapped QK^T (lane-local q), in-register softmax, packed P,
// PV from LDS, normalized store.
#define KSTR 144
#define VSTR 464
#define PWB  7424
__global__ __launch_bounds__(832, 1) void k_attn(
    const u16* __restrict__ qg, const u16* __restrict__ kg, const u16* __restrict__ vTg,
    const u16* __restrict__ rphb, const u16* __restrict__ rpwb,
    u16* __restrict__ ao)
{
  extern __shared__ __align__(16) char asmem[];
  char* Klds = asmem;                    // 208 x 144B (128 used)
  char* Vlds = asmem + 29952;            // 64 x 464B (448 used)
  const int tid = threadIdx.x, lane = tid & 63, wvi = tid >> 6;  // 0..12
  const int l16 = lane & 15, lk = lane >> 4;
  char*  wbase = asmem + 59648 + wvi * PWB;
  float* relT  = (float*)wbase;          // [16][68] f32
  u32*   Pp    = (u32*)wbase;            // [16][116] u32 (alias; disjoint lifetime)

  const int bh = blockIdx.x;
  const int hh = bh >> 6, bb = bh & 63;
  const u16* qb = qg  + (size_t)bh * SP * HD;
  const u16* kb = kg  + (size_t)bh * SP * HD;
  const u16* vb = vTg + (size_t)bh * HD * SPV;

  // ---- cooperative K/V staging (reg-staged, padded strides) ----
  for (int c = tid; c < 1664; c += 832){           // K: 208 rows x 8 chunks
    int row = c >> 3, colb = (c & 7) << 4;
    short8 d = *(const short8*)((const char*)kb + row*128 + colb);
    *(short8*)(Klds + row*KSTR + colb) = d;
  }
  for (int c = tid; c < 1792; c += 832){           // V: 64 rows x 28 chunks
    int row = c / 28, colb = (c - row*28) << 4;
    short8 d = *(const short8*)((const char*)vb + row*448 + colb);
    *(short8*)(Vlds + row*VSTR + colb) = d;
  }
  __syncthreads();

  const int mt = wvi;
  const short8 a0 = *(const short8*)(qb + (size_t)(mt*16 + l16) * HD + lk*8);
  const short8 a1 = *(const short8*)(qb + (size_t)(mt*16 + l16) * HD + 32 + lk*8);

  // rel tables via MFMA: lane(l16,lk) reg i = T[delta=dt*16+lk*4+i][q=l16]
  {
    f32x4 z = {0.f,0.f,0.f,0.f};
    f32x4 racc[2][2] = {{z,z},{z,z}};
    #pragma unroll
    for (int dt = 0; dt < 2; ++dt){
      short8 h0 = *(const short8*)(rphb + (size_t)(dt*16 + l16) * 64 + lk*8);
      short8 h1 = *(const short8*)(rphb + (size_t)(dt*16 + l16) * 64 + 32 + lk*8);
      short8 w0 = *(const short8*)(rpwb + (size_t)(dt*16 + l16) * 64 + lk*8);
      short8 w1 = *(const short8*)(rpwb + (size_t)(dt*16 + l16) * 64 + 32 + lk*8);
      racc[0][dt] = __builtin_amdgcn_mfma_f32_16x16x32_bf16(h0, a0, racc[0][dt], 0, 0, 0);
      racc[0][dt] = __builtin_amdgcn_mfma_f32_16x16x32_bf16(h1, a1, racc[0][dt], 0, 0, 0);
      racc[1][dt] = __builtin_amdgcn_mfma_f32_16x16x32_bf16(w0, a0, racc[1][dt], 0, 0, 0);
      racc[1][dt] = __builtin_amdgcn_mfma_f32_16x16x32_bf16(w1, a1, racc[1][dt], 0, 0, 0);
    }
    #pragma unroll
    for (int t = 0; t < 2; ++t)
      #pragma unroll
      for (int dt = 0; dt < 2; ++dt)
        *(f32x4*)(relT + l16*68 + t*32 + dt*16 + lk*4) = racc[t][dt];
  }
  DS_FENCE();

  // bias as MFMA C-in: sacc[nt][i] = Th[q][qh+13-kh] + Tw[q][qw+13-kw]
  int qr = mt*16 + l16;
  int qrc = qr > HW-1 ? HW-1 : qr;
  int qh = qrc / 14, qw = qrc - 14*qh;
  const float* rrow = relT + l16*68;
  const int dh0 = qh + 13, dw0 = 32 + qw + 13;
  const int lk4 = lk*4;

  f32x4 sacc[13];
  #pragma unroll
  for (int nt = 0; nt < 13; ++nt){
    #pragma unroll
    for (int i = 0; i < 4; ++i){
      int k = nt*16 + lk4 + i;
      int kh = (k * 4682) >> 16;
      if (nt == 12 && kh > 13) kh = 13;
      int kw = k - kh*14;
      float bias = rrow[dh0 - kh] + rrow[dw0 - kw];
      sacc[nt][i] = (nt == 12 && lk != 0) ? -1e30f : bias;
    }
  }

  // QK^T swapped from K LDS (K pre-scaled by 0.125 at the GEMM epilogue)
  #pragma unroll
  for (int nt = 0; nt < 13; ++nt){
    int row = nt*16 + l16;
    short8 b0 = *(const short8*)(Klds + row*KSTR + lk*16);
    short8 b1 = *(const short8*)(Klds + row*KSTR + 64 + lk*16);
    sacc[nt] = __builtin_amdgcn_mfma_f32_16x16x32_bf16(b0, a0, sacc[nt], 0, 0, 0);
    sacc[nt] = __builtin_amdgcn_mfma_f32_16x16x32_bf16(b1, a1, sacc[nt], 0, 0, 0);
  }

  // softmax for q=l16: in-register tree + 2 shfl_xor across lk
  float m;
  {
    float t0[13];
    #pragma unroll
    for (int nt = 0; nt < 13; ++nt)
      t0[nt] = fmaxf(fmaxf(sacc[nt][0], sacc[nt][1]), fmaxf(sacc[nt][2], sacc[nt][3]));
    float a01 = fmaxf(t0[0], t0[1]),  a23 = fmaxf(t0[2], t0[3]);
    float a45 = fmaxf(t0[4], t0[5]),  a67 = fmaxf(t0[6], t0[7]);
    float a89 = fmaxf(t0[8], t0[9]),  aab = fmaxf(t0[10], t0[11]);
    m = fmaxf(fmaxf(fmaxf(a01, a23), fmaxf(a45, a67)), fmaxf(fmaxf(a89, aab), t0[12]));
  }
  m = fmaxf(m, __shfl_xor(m, 16, 64));
  m = fmaxf(m, __shfl_xor(m, 32, 64));
  float sum;
  {
    float s4[13];
    #pragma unroll
    for (int nt = 0; nt < 13; ++nt){
      #pragma unroll
      for (int i = 0; i < 4; ++i)
        sacc[nt][i] = __expf(sacc[nt][i] - m);
      s4[nt] = (sacc[nt][0] + sacc[nt][1]) + (sacc[nt][2] + sacc[nt][3]);
    }
    float b01 = s4[0]+s4[1], b23 = s4[2]+s4[3], b45 = s4[4]+s4[5];
    float b67 = s4[6]+s4[7], b89 = s4[8]+s4[9], bab = s4[10]+s4[11];
    sum = ((b01+b23) + (b45+b67)) + ((b89+bab) + s4[12]);
  }
  sum += __shfl_xor(sum, 16, 64);
  sum += __shfl_xor(sum, 32, 64);
  float inv = 1.0f / sum;

  // pack P -> Pp[q=l16][k/2] (aliases relT; DS-order fence first)
  DS_FENCE();
  u32* prow = Pp + l16*116;
  #pragma unroll
  for (int nt = 0; nt < 13; ++nt){
    u32x2 wpk;
    wpk[0] = cvtpk_bf16(sacc[nt][0], sacc[nt][1]);
    wpk[1] = cvtpk_bf16(sacc[nt][2], sacc[nt][3]);
    *(u32x2*)(prow + nt*8 + lk*2) = wpk;
  }
  { u32x2 zz = {0u, 0u}; *(u32x2*)(prow + 104 + lk*2) = zz; }
  DS_FENCE();

  // PV: pa from Pp, V^T fragments from V LDS
  f32x4 z = {0.f,0.f,0.f,0.f};
  f32x4 oacc[4] = {z,z,z,z};
  #pragma unroll
  for (int kt = 0; kt < 7; ++kt){
    short8 pa = *(const short8*)(prow + kt*16 + lk4);
    #pragma unroll
    for (int dt = 0; dt < 4; ++dt){
      short8 bv = *(const short8*)(Vlds + (dt*16 + l16)*VSTR + kt*64 + lk*16);
      oacc[dt] = __builtin_amdgcn_mfma_f32_16x16x32_bf16(bv, pa, oacc[dt], 0, 0, 0);
    }
  }
  int qrow = mt*16 + l16;
  if (qrow < HW){
    u16* orow = ao + ((size_t)bb * HW + qrow) * DIM + hh * HD;
    #pragma unroll
    for (int dt = 0; dt < 4; ++dt){
      u32 lo = cvtpk_bf16(oacc[dt][0]*inv, oacc[dt][1]*inv);
      u32 hi = cvtpk_bf16(oacc[dt][2]*inv, oacc[dt][3]*inv);
      u32* dst = (u32*)(orow + dt*16 + lk4);
      dst[0] = lo; dst[1] = hi;
    }
  }
}

extern "C" void kernel_launch(void* const* d_in, const int* in_sizes, int n_in,
                              void* d_out, int out_size, void* d_ws, size_t ws_size,
                              hipStream_t stream)
{
  const float* x      = (const float*)d_in[0];
  const float* qkv_w  = (const float*)d_in[1];
  const float* qkv_b  = (const float*)d_in[2];
  const float* proj_w = (const float*)d_in[3];
  const float* proj_b = (const float*)d_in[4];
  const float* rph    = (const float*)d_in[5];
  const float* rpw    = (const float*)d_in[6];
  float* out = (float*)d_out;
  char* ws = (char*)d_ws;

  size_t off = 0;
  auto alloc = [&](size_t b){ size_t r = off; off += (b + 255) & ~(size_t)255; return r; };
  u16* wqkvT = (u16*)(ws + alloc((size_t)3072*1024*2));
  u16* wprojT= (u16*)(ws + alloc((size_t)1024*1024*2));
  u16* qg    = (u16*)(ws + alloc((size_t)NBH*SP*HD*2));
  u16* kg    = (u16*)(ws + alloc((size_t)NBH*SP*HD*2));
  u16* vTg   = (u16*)(ws + alloc((size_t)NBH*HD*SPV*2));
  u16* rphb  = (u16*)(ws + alloc((size_t)32*64*2));
  u16* rpwb  = (u16*)(ws + alloc((size_t)32*64*2));
  u16* xb    = (u16*)(ws + alloc((size_t)12544*1024*2));
  u16* ao    = xb;   // disjoint lifetimes

  hipFuncSetAttribute((const void*)k_g256<0>, hipFuncAttributeMaxDynamicSharedMemorySize, 131072);
  hipFuncSetAttribute((const void*)k_g256<1>, hipFuncAttributeMaxDynamicSharedMemorySize, 131072);
  hipFuncSetAttribute((const void*)k_attn,    hipFuncAttributeMaxDynamicSharedMemorySize, 156160);

  hipMemsetAsync(vTg, 0, (size_t)NBH*HD*SPV*2, stream);

  k_xcvt<<<(12544*1024/8 + 255)/256, 256, 0, stream>>>(x, xb, 12544*1024/8);
  k_wT<<<dim3(96, 32), 256, 0, stream>>>(qkv_w, wqkvT, 1024, 3072);
  k_wT<<<dim3(32, 32), 256, 0, stream>>>(proj_w, wprojT, 1024, 1024);
  k_rprep<<<1, 256, 0, stream>>>(rph, rpw, rphb, rpwb);

  k_g256<0><<<49*12, 512, 131072, stream>>>(xb, wqkvT, qkv_b, qg, kg, vTg, nullptr,
                                            1024, 3072, 49, 12);
  k_attn<<<1024, 832, 156160, stream>>>(qg, kg, vTg, rphb, rpwb, ao);
  k_g256<1><<<49*4, 512, 131072, stream>>>(ao, wprojT, proj_b, nullptr, nullptr, nullptr, out,
                                           1024, 1024, 49, 4);
}